// Round 4
// baseline (598.160 us; speedup 1.0000x reference)
//
#include <hip/hip_runtime.h>
#include <hip/hip_bf16.h>

#define FEAT 128
#define NRELS 16
#define BKT_SZ 32          // dst nodes per bucket
#define PCHUNK 4096        // edges per partition block (16 per thread)

using short8 = __attribute__((ext_vector_type(8))) short;
using f32x4  = __attribute__((ext_vector_type(4))) float;

__device__ inline ushort f2bf(float x) {
    union { float f; unsigned int u; } v; v.f = x;
    unsigned int u = v.u;
    unsigned int r = (u + 0x7fffu + ((u >> 16) & 1u)) >> 16;  // RNE
    return (ushort)r;
}
__device__ inline float bf2f(ushort b) {
    union { unsigned int u; float f; } v; v.u = ((unsigned int)b) << 16;
    return v.f;
}

// ---------------------------------------------------------------------------
// Pack h -> bf16 MFMA A-slabs:
//   hpack[(mblk*4+ks)*64 + lane][j] = h[mblk*16 + (lane&15)][ks*32 + (lane>>4)*8 + j]
// ---------------------------------------------------------------------------
__global__ __launch_bounds__(256) void pack_h_kernel(
    const float* __restrict__ h, ushort* __restrict__ hpack, int n_nodes, int nmblk)
{
    int t = blockIdx.x * 256 + threadIdx.x;
    if (t >= nmblk * 256) return;
    int lane = t & 63;
    int mblk = t >> 8;
    int ks   = (t >> 6) & 3;
    int row  = mblk * 16 + (lane & 15);
    int k0   = ks * 32 + (lane >> 4) * 8;

    ushort u[8] = {0, 0, 0, 0, 0, 0, 0, 0};
    if (row < n_nodes) {
        const float* p = h + (size_t)row * FEAT + k0;
        float4 a = *reinterpret_cast<const float4*>(p);
        float4 b = *reinterpret_cast<const float4*>(p + 4);
        u[0] = f2bf(a.x); u[1] = f2bf(a.y); u[2] = f2bf(a.z); u[3] = f2bf(a.w);
        u[4] = f2bf(b.x); u[5] = f2bf(b.y); u[6] = f2bf(b.z); u[7] = f2bf(b.w);
    }
    *reinterpret_cast<short8*>(hpack + (size_t)t * 8) = *reinterpret_cast<short8*>(u);
}

// ---------------------------------------------------------------------------
// Pack W^T -> bf16 MFMA slabs (slab row index = output feature):
//   wpack[((r*8+fb)*4+ks)*64 + lane][j] = W[r][ks*32+(lane>>4)*8+j][fb*16+(lane&15)]
// ---------------------------------------------------------------------------
__global__ __launch_bounds__(256) void pack_w_kernel(
    const float* __restrict__ W, ushort* __restrict__ wpack)
{
    int t = blockIdx.x * 256 + threadIdx.x;
    if (t >= NRELS * 8 * 4 * 64) return;
    int lane = t & 63;
    int ks   = (t >> 6) & 3;
    int fb   = (t >> 8) & 7;
    int r    = t >> 11;
    int k0   = ks * 32 + (lane >> 4) * 8;
    int f    = fb * 16 + (lane & 15);

    ushort u[8];
    #pragma unroll
    for (int j = 0; j < 8; ++j)
        u[j] = f2bf(W[((size_t)r * FEAT + (k0 + j)) * FEAT + f]);
    *reinterpret_cast<short8*>(wpack + (size_t)t * 8) = *reinterpret_cast<short8*>(u);
}

// ---------------------------------------------------------------------------
// proj[r][n][f] = h[n][:] @ W[r][:][f]  -- no LDS, no barriers.
// ---------------------------------------------------------------------------
__global__ __launch_bounds__(256) void proj2_kernel(
    const ushort* __restrict__ hpack, const ushort* __restrict__ wpack,
    ushort* __restrict__ proj, int n_nodes, int nmblk)
{
    const int lane = threadIdx.x & 63;
    const int wv   = threadIdx.x >> 6;
    const int rr   = blockIdx.y;

    const short8* wp = reinterpret_cast<const short8*>(wpack);
    const short8* hp = reinterpret_cast<const short8*>(hpack);

    short8 X[8][4];
    #pragma unroll
    for (int fb = 0; fb < 8; ++fb)
        #pragma unroll
        for (int ks = 0; ks < 4; ++ks)
            X[fb][ks] = wp[(((rr * 8 + fb) * 4 + ks) << 6) + lane];

    const int wgid    = blockIdx.x * 4 + wv;
    const int wstride = gridDim.x * 4;

    for (int mb = wgid; mb < nmblk; mb += wstride) {
        short8 Y[4];
        #pragma unroll
        for (int ks = 0; ks < 4; ++ks)
            Y[ks] = hp[((mb * 4 + ks) << 6) + lane];

        f32x4 acc[8];
        #pragma unroll
        for (int fb = 0; fb < 8; ++fb) acc[fb] = f32x4{0.f, 0.f, 0.f, 0.f};

        #pragma unroll
        for (int ks = 0; ks < 4; ++ks)
            #pragma unroll
            for (int fb = 0; fb < 8; ++fb)
                acc[fb] = __builtin_amdgcn_mfma_f32_16x16x32_bf16(X[fb][ks], Y[ks], acc[fb], 0, 0, 0);

        const int node = mb * 16 + (lane & 15);
        if (node < n_nodes) {
            ushort* prow = proj + ((size_t)rr * n_nodes + node) * FEAT + (lane >> 4) * 4;
            #pragma unroll
            for (int fb = 0; fb < 8; ++fb) {
                unsigned d0 = (unsigned)f2bf(acc[fb][0]) | ((unsigned)f2bf(acc[fb][1]) << 16);
                unsigned d1 = (unsigned)f2bf(acc[fb][2]) | ((unsigned)f2bf(acc[fb][3]) << 16);
                uint2 d; d.x = d0; d.y = d1;
                *reinterpret_cast<uint2*>(prow + fb * 16) = d;
            }
        }
    }
}

// ---------------------------------------------------------------------------
// Bucket histogram: gcnt[b] = #edges with dst>>5 == b  (LDS-staged)
// ---------------------------------------------------------------------------
__global__ __launch_bounds__(256) void bhist_kernel(
    const int* __restrict__ dst, int* __restrict__ gcnt, int n_edges, int nbkt)
{
    __shared__ int cnt[1024];
    for (int i = threadIdx.x; i < nbkt; i += 256) cnt[i] = 0;
    __syncthreads();
    int i = blockIdx.x * 256 + threadIdx.x;
    int stride = gridDim.x * 256;
    for (; i < n_edges; i += stride)
        atomicAdd(&cnt[dst[i] >> 5], 1);
    __syncthreads();
    for (int i2 = threadIdx.x; i2 < nbkt; i2 += 256)
        if (cnt[i2] > 0) atomicAdd(&gcnt[i2], cnt[i2]);
}

// ---------------------------------------------------------------------------
// Tiny scan over nbkt (<=1024) bins -> boffs[nbkt+1], gcur copy
// ---------------------------------------------------------------------------
__global__ __launch_bounds__(1024) void bscan_kernel(
    const int* __restrict__ gcnt, int* __restrict__ boffs,
    int* __restrict__ gcur, int nbkt)
{
    __shared__ int part[1024];
    const int tid = threadIdx.x;
    part[tid] = (tid < nbkt) ? gcnt[tid] : 0;
    __syncthreads();
    for (int d = 1; d < 1024; d <<= 1) {
        int v = (tid >= d) ? part[tid - d] : 0;
        __syncthreads();
        part[tid] += v;
        __syncthreads();
    }
    int excl = (tid > 0) ? part[tid - 1] : 0;
    if (tid < nbkt) { boffs[tid] = excl; gcur[tid] = excl; }
    if (tid == 1023) boffs[nbkt] = part[1023];
}

// ---------------------------------------------------------------------------
// Partition: LDS-staged two-pass scatter -> recs grouped by bucket.
// rec.x = src | rel<<15 | (dst&31)<<19 ; rec.y = norm bits
// ---------------------------------------------------------------------------
__global__ __launch_bounds__(256) void partition_kernel(
    const int* __restrict__ src, const int* __restrict__ dst,
    const int* __restrict__ rel, const float* __restrict__ norm,
    int* __restrict__ gcur, uint2* __restrict__ recs, int n_edges, int nbkt)
{
    __shared__ int cnt[1024];
    __shared__ int base[1024];
    __shared__ int cur[1024];
    __shared__ uint2 stage[PCHUNK];
    __shared__ ushort sbkt[PCHUNK];

    const int tid = threadIdx.x;
    const int c0 = blockIdx.x * PCHUNK;

    for (int i = tid; i < nbkt; i += 256) { cnt[i] = 0; cur[i] = 0; }
    __syncthreads();

    #pragma unroll
    for (int j = 0; j < PCHUNK / 256; ++j) {
        int slot = j * 256 + tid;
        int e = c0 + slot;
        if (e < n_edges) {
            int d = dst[e];
            int b = d >> 5;
            uint2 r;
            r.x = (unsigned)src[e] | ((unsigned)rel[e] << 15) | ((unsigned)(d & 31) << 19);
            r.y = __float_as_uint(norm[e]);
            stage[slot] = r;
            sbkt[slot] = (ushort)b;
            atomicAdd(&cnt[b], 1);
        } else {
            sbkt[slot] = 0xffffu;
        }
    }
    __syncthreads();

    for (int i = tid; i < nbkt; i += 256)
        if (cnt[i] > 0) base[i] = atomicAdd(&gcur[i], cnt[i]);
    __syncthreads();

    #pragma unroll
    for (int j = 0; j < PCHUNK / 256; ++j) {
        int slot = j * 256 + tid;
        ushort b = sbkt[slot];
        if (b != 0xffffu) {
            int rank = atomicAdd(&cur[b], 1);
            recs[base[b] + rank] = stage[slot];
        }
    }
}

// ---------------------------------------------------------------------------
// Bucket gather: one block per 32-dst bucket; LDS f32 accumulator;
// 8 waves, wave-per-edge, 4-deep pipeline; fused ReLU + coalesced store.
// ---------------------------------------------------------------------------
__global__ __launch_bounds__(512) void bgather_kernel(
    const ushort* __restrict__ proj, const uint2* __restrict__ recs,
    const int* __restrict__ boffs, float* __restrict__ out, int n_nodes)
{
    __shared__ float acc[BKT_SZ * FEAT];   // 16 KB

    const int tid  = threadIdx.x;
    const int lane = tid & 63;
    const int wv   = tid >> 6;             // 0..7

    for (int i = tid; i < BKT_SZ * FEAT; i += 512) acc[i] = 0.f;
    __syncthreads();

    const int beg = boffs[blockIdx.x];
    const int end = boffs[blockIdx.x + 1];

    for (int e = beg + wv; e < end; e += 32) {   // 8 waves x 4-deep
        uint2 r0, r1, r2, r3;
        r0 = (e          < end) ? recs[e]          : make_uint2(0u, 0u);
        r1 = (e + 8      < end) ? recs[e + 8]      : make_uint2(0u, 0u);
        r2 = (e + 16     < end) ? recs[e + 16]     : make_uint2(0u, 0u);
        r3 = (e + 24     < end) ? recs[e + 24]     : make_uint2(0u, 0u);

        unsigned v0 = *reinterpret_cast<const unsigned*>(
            proj + ((size_t)((r0.x >> 15) & 0xfu) * n_nodes + (r0.x & 0x7fffu)) * FEAT + lane * 2);
        unsigned v1 = *reinterpret_cast<const unsigned*>(
            proj + ((size_t)((r1.x >> 15) & 0xfu) * n_nodes + (r1.x & 0x7fffu)) * FEAT + lane * 2);
        unsigned v2 = *reinterpret_cast<const unsigned*>(
            proj + ((size_t)((r2.x >> 15) & 0xfu) * n_nodes + (r2.x & 0x7fffu)) * FEAT + lane * 2);
        unsigned v3 = *reinterpret_cast<const unsigned*>(
            proj + ((size_t)((r3.x >> 15) & 0xfu) * n_nodes + (r3.x & 0x7fffu)) * FEAT + lane * 2);

        {
            float nm = __uint_as_float(r0.y);
            float* a = &acc[((r0.x >> 19) & 31u) * FEAT + lane * 2];
            atomicAdd(a + 0, bf2f((ushort)(v0 & 0xffffu)) * nm);
            atomicAdd(a + 1, bf2f((ushort)(v0 >> 16)) * nm);
        }
        {
            float nm = __uint_as_float(r1.y);
            float* a = &acc[((r1.x >> 19) & 31u) * FEAT + lane * 2];
            atomicAdd(a + 0, bf2f((ushort)(v1 & 0xffffu)) * nm);
            atomicAdd(a + 1, bf2f((ushort)(v1 >> 16)) * nm);
        }
        {
            float nm = __uint_as_float(r2.y);
            float* a = &acc[((r2.x >> 19) & 31u) * FEAT + lane * 2];
            atomicAdd(a + 0, bf2f((ushort)(v2 & 0xffffu)) * nm);
            atomicAdd(a + 1, bf2f((ushort)(v2 >> 16)) * nm);
        }
        {
            float nm = __uint_as_float(r3.y);
            float* a = &acc[((r3.x >> 19) & 31u) * FEAT + lane * 2];
            atomicAdd(a + 0, bf2f((ushort)(v3 & 0xffffu)) * nm);
            atomicAdd(a + 1, bf2f((ushort)(v3 >> 16)) * nm);
        }
    }
    __syncthreads();

    const int node0 = blockIdx.x * BKT_SZ;
    for (int i = tid; i < BKT_SZ * (FEAT / 4); i += 512) {
        int n  = i >> 5;          // node within bucket
        int f4 = i & 31;          // float4 group
        int node = node0 + n;
        if (node >= n_nodes) break;
        float4 v = *reinterpret_cast<float4*>(&acc[n * FEAT + f4 * 4]);
        v.x = fmaxf(v.x, 0.f);
        v.y = fmaxf(v.y, 0.f);
        v.z = fmaxf(v.z, 0.f);
        v.w = fmaxf(v.w, 0.f);
        *reinterpret_cast<float4*>(out + (size_t)node * FEAT + f4 * 4) = v;
    }
}

// ---------------------------------------------------------------------------
// Fallback (small ws): LDS proj + atomic edge path
// ---------------------------------------------------------------------------
constexpr int BM = 64;

__global__ __launch_bounds__(256) void proj_kernel(
    const float* __restrict__ h, const float* __restrict__ W,
    ushort* __restrict__ proj, int n_nodes, int r0)
{
    __shared__ ushort Wt[128][136];
    __shared__ ushort hs[BM][136];

    const int tid  = threadIdx.x;
    const int rel  = r0 + blockIdx.y;
    const float* Wg = W + (size_t)rel * FEAT * FEAT;

    #pragma unroll
    for (int it = 0; it < 16; ++it) {
        int f = (it * 256 + tid) * 4;
        int k = f >> 7, n = f & 127;
        float4 w4 = *reinterpret_cast<const float4*>(Wg + f);
        Wt[n + 0][k] = f2bf(w4.x);
        Wt[n + 1][k] = f2bf(w4.y);
        Wt[n + 2][k] = f2bf(w4.z);
        Wt[n + 3][k] = f2bf(w4.w);
    }

    const int lane = tid & 63;
    const int wave = tid >> 6;
    const int r    = lane & 15;
    const int kgrp = lane >> 4;

    ushort* projr = proj + (size_t)blockIdx.y * n_nodes * FEAT;
    const int nchunks = (n_nodes + BM - 1) / BM;

    for (int c = blockIdx.x; c < nchunks; c += gridDim.x) {
        const int m0 = c * BM;
        __syncthreads();
        #pragma unroll
        for (int it = 0; it < 8; ++it) {
            int f = (it * 256 + tid) * 4;
            int m = f >> 7, k = f & 127;
            int row = m0 + m;
            float4 v = make_float4(0.f, 0.f, 0.f, 0.f);
            if (row < n_nodes)
                v = *reinterpret_cast<const float4*>(h + (size_t)row * FEAT + k);
            ushort4 u;
            u.x = f2bf(v.x); u.y = f2bf(v.y); u.z = f2bf(v.z); u.w = f2bf(v.w);
            *reinterpret_cast<ushort4*>(&hs[m][k]) = u;
        }
        __syncthreads();

        f32x4 acc[8];
        #pragma unroll
        for (int i = 0; i < 8; ++i) acc[i] = f32x4{0.f, 0.f, 0.f, 0.f};

        #pragma unroll
        for (int kk = 0; kk < 4; ++kk) {
            const int kbase = kk * 32 + kgrp * 8;
            short8 a = *reinterpret_cast<const short8*>(&hs[wave * 16 + r][kbase]);
            #pragma unroll
            for (int ct = 0; ct < 8; ++ct) {
                short8 b = *reinterpret_cast<const short8*>(&Wt[ct * 16 + r][kbase]);
                acc[ct] = __builtin_amdgcn_mfma_f32_16x16x32_bf16(a, b, acc[ct], 0, 0, 0);
            }
        }

        #pragma unroll
        for (int ct = 0; ct < 8; ++ct) {
            #pragma unroll
            for (int i = 0; i < 4; ++i) {
                int row = m0 + wave * 16 + kgrp * 4 + i;
                if (row < n_nodes)
                    projr[(size_t)row * FEAT + ct * 16 + r] = f2bf(acc[ct][i]);
            }
        }
    }
}

__global__ __launch_bounds__(256) void edge_kernel(
    const ushort* __restrict__ proj, const float* __restrict__ norm,
    const int* __restrict__ src, const int* __restrict__ dst,
    const int* __restrict__ rel, float* __restrict__ out,
    int n_edges, int n_nodes, int r0, int r1)
{
    const int lane = threadIdx.x & 63;
    int gw = (int)((blockIdx.x * blockDim.x + threadIdx.x) >> 6);
    const int nw = (int)((gridDim.x * blockDim.x) >> 6);

    for (int e = gw; e < n_edges; e += nw) {
        int rr = rel[e];
        if (rr < r0 || rr >= r1) continue;
        int s = src[e];
        int d = dst[e];
        float nm = norm[e];
        const ushort* prow = proj + ((size_t)(rr - r0) * n_nodes + s) * FEAT;
        unsigned int v = *reinterpret_cast<const unsigned int*>(prow + lane * 2);
        float x0 = bf2f((ushort)(v & 0xffffu)) * nm;
        float x1 = bf2f((ushort)(v >> 16)) * nm;
        float* o = out + (size_t)d * FEAT + lane * 2;
        atomicAdd(o + 0, x0);
        atomicAdd(o + 1, x1);
    }
}

__global__ __launch_bounds__(256) void relu_kernel(float4* out, int n4)
{
    int i = blockIdx.x * blockDim.x + threadIdx.x;
    int stride = gridDim.x * blockDim.x;
    for (; i < n4; i += stride) {
        float4 v = out[i];
        v.x = fmaxf(v.x, 0.f);
        v.y = fmaxf(v.y, 0.f);
        v.z = fmaxf(v.z, 0.f);
        v.w = fmaxf(v.w, 0.f);
        out[i] = v;
    }
}

extern "C" void kernel_launch(void* const* d_in, const int* in_sizes, int n_in,
                              void* d_out, int out_size, void* d_ws, size_t ws_size,
                              hipStream_t stream)
{
    const float* h    = (const float*)d_in[0];
    const float* W    = (const float*)d_in[1];
    const float* norm = (const float*)d_in[2];
    const int*   src  = (const int*)d_in[3];
    const int*   dst  = (const int*)d_in[4];
    const int*   rel  = (const int*)d_in[5];
    float* out = (float*)d_out;

    const int n_nodes = in_sizes[0] / FEAT;   // 20000
    const int n_edges = in_sizes[3];          // 640000
    const int nmblk   = (n_nodes + 15) / 16;
    const int nbkt    = (n_nodes + BKT_SZ - 1) / BKT_SZ;   // 625

    // ws layout
    const size_t projB    = (size_t)NRELS * n_nodes * FEAT * sizeof(ushort);
    const size_t recsOff  = (projB + 255) & ~(size_t)255;
    const size_t recsB    = (size_t)n_edges * sizeof(uint2);
    const size_t cntOff   = (recsOff + recsB + 255) & ~(size_t)255;
    const size_t cntB     = ((size_t)(nbkt + 1) * 4 + 255) & ~(size_t)255;
    const size_t offOff   = cntOff + cntB;
    const size_t curOff   = offOff + cntB;
    const size_t hpackOff = curOff + cntB;
    const size_t hpackB   = ((size_t)nmblk * 256 * 8 * sizeof(ushort) + 255) & ~(size_t)255;
    const size_t wpackOff = hpackOff + hpackB;
    const size_t wpackB   = (size_t)NRELS * 8 * 4 * 64 * 8 * sizeof(ushort);
    const size_t need     = wpackOff + wpackB;

    if (ws_size >= need && n_nodes < 32768 && nbkt <= 1024) {
        ushort* proj  = (ushort*)d_ws;
        uint2*  recs  = (uint2*)((char*)d_ws + recsOff);
        int*    gcnt  = (int*)((char*)d_ws + cntOff);
        int*    boffs = (int*)((char*)d_ws + offOff);
        int*    gcur  = (int*)((char*)d_ws + curOff);
        ushort* hpack = (ushort*)((char*)d_ws + hpackOff);
        ushort* wpack = (ushort*)((char*)d_ws + wpackOff);

        pack_h_kernel<<<nmblk, 256, 0, stream>>>(h, hpack, n_nodes, nmblk);
        pack_w_kernel<<<(NRELS * 8 * 4 * 64 + 255) / 256, 256, 0, stream>>>(W, wpack);
        dim3 g1(128, NRELS);
        proj2_kernel<<<g1, 256, 0, stream>>>(hpack, wpack, proj, n_nodes, nmblk);

        hipMemsetAsync(gcnt, 0, (size_t)(nbkt + 1) * 4, stream);
        bhist_kernel<<<256, 256, 0, stream>>>(dst, gcnt, n_edges, nbkt);
        bscan_kernel<<<1, 1024, 0, stream>>>(gcnt, boffs, gcur, nbkt);
        partition_kernel<<<(n_edges + PCHUNK - 1) / PCHUNK, 256, 0, stream>>>(
            src, dst, rel, norm, gcur, recs, n_edges, nbkt);
        bgather_kernel<<<nbkt, 512, 0, stream>>>(proj, recs, boffs, out, n_nodes);
    } else {
        // fallback: relation-chunked atomic path
        ushort* proj = (ushort*)d_ws;
        hipMemsetAsync(out, 0, (size_t)out_size * sizeof(float), stream);
        const size_t perRel = (size_t)n_nodes * FEAT * sizeof(ushort);
        int rc = (int)(ws_size / perRel);
        if (rc < 1) rc = 1;
        if (rc > NRELS) rc = NRELS;
        for (int r0 = 0; r0 < NRELS; r0 += rc) {
            const int rcc = (rc < NRELS - r0) ? rc : (NRELS - r0);
            dim3 g1(32, rcc);
            proj_kernel<<<g1, 256, 0, stream>>>(h, W, proj, n_nodes, r0);
            edge_kernel<<<1024, 256, 0, stream>>>(proj, norm, src, dst, rel, out,
                                                  n_edges, n_nodes, r0, r0 + rcc);
        }
        relu_kernel<<<2048, 256, 0, stream>>>((float4*)out, out_size / 4);
    }
}

// Round 5
// 117.080 us; speedup vs baseline: 5.1090x; 5.1090x over previous
//
#include <hip/hip_runtime.h>
#include <hip/hip_bf16.h>

#define FEAT 128
#define NRELS 16
#define BKT_SZ 32          // dst nodes per bucket
#define PCHUNK 4096        // edges per partition block (16 per thread)

using short8 = __attribute__((ext_vector_type(8))) short;
using f32x4  = __attribute__((ext_vector_type(4))) float;

__device__ inline ushort f2bf(float x) {
    union { float f; unsigned int u; } v; v.f = x;
    unsigned int u = v.u;
    unsigned int r = (u + 0x7fffu + ((u >> 16) & 1u)) >> 16;  // RNE
    return (ushort)r;
}
__device__ inline float bf2f(ushort b) {
    union { unsigned int u; float f; } v; v.u = ((unsigned int)b) << 16;
    return v.f;
}

// ---------------------------------------------------------------------------
// Pack h -> bf16 MFMA A-slabs:
//   hpack[(mblk*4+ks)*64 + lane][j] = h[mblk*16 + (lane&15)][ks*32 + (lane>>4)*8 + j]
// ---------------------------------------------------------------------------
__global__ __launch_bounds__(256) void pack_h_kernel(
    const float* __restrict__ h, ushort* __restrict__ hpack, int n_nodes, int nmblk)
{
    int t = blockIdx.x * 256 + threadIdx.x;
    if (t >= nmblk * 256) return;
    int lane = t & 63;
    int mblk = t >> 8;
    int ks   = (t >> 6) & 3;
    int row  = mblk * 16 + (lane & 15);
    int k0   = ks * 32 + (lane >> 4) * 8;

    ushort u[8] = {0, 0, 0, 0, 0, 0, 0, 0};
    if (row < n_nodes) {
        const float* p = h + (size_t)row * FEAT + k0;
        float4 a = *reinterpret_cast<const float4*>(p);
        float4 b = *reinterpret_cast<const float4*>(p + 4);
        u[0] = f2bf(a.x); u[1] = f2bf(a.y); u[2] = f2bf(a.z); u[3] = f2bf(a.w);
        u[4] = f2bf(b.x); u[5] = f2bf(b.y); u[6] = f2bf(b.z); u[7] = f2bf(b.w);
    }
    *reinterpret_cast<short8*>(hpack + (size_t)t * 8) = *reinterpret_cast<short8*>(u);
}

// ---------------------------------------------------------------------------
// Pack W^T -> bf16 MFMA slabs (slab row index = output feature):
//   wpack[((r*8+fb)*4+ks)*64 + lane][j] = W[r][ks*32+(lane>>4)*8+j][fb*16+(lane&15)]
// ---------------------------------------------------------------------------
__global__ __launch_bounds__(256) void pack_w_kernel(
    const float* __restrict__ W, ushort* __restrict__ wpack)
{
    int t = blockIdx.x * 256 + threadIdx.x;
    if (t >= NRELS * 8 * 4 * 64) return;
    int lane = t & 63;
    int ks   = (t >> 6) & 3;
    int fb   = (t >> 8) & 7;
    int r    = t >> 11;
    int k0   = ks * 32 + (lane >> 4) * 8;
    int f    = fb * 16 + (lane & 15);

    ushort u[8];
    #pragma unroll
    for (int j = 0; j < 8; ++j)
        u[j] = f2bf(W[((size_t)r * FEAT + (k0 + j)) * FEAT + f]);
    *reinterpret_cast<short8*>(wpack + (size_t)t * 8) = *reinterpret_cast<short8*>(u);
}

// ---------------------------------------------------------------------------
// proj[r][n][f] = h[n][:] @ W[r][:][f]  -- no LDS, no barriers.
// D = mfma(Wfrag, hfrag): node = lane&15, feat = fb*16 + (lane>>4)*4 + i
// ---------------------------------------------------------------------------
__global__ __launch_bounds__(256) void proj2_kernel(
    const ushort* __restrict__ hpack, const ushort* __restrict__ wpack,
    ushort* __restrict__ proj, int n_nodes, int nmblk)
{
    const int lane = threadIdx.x & 63;
    const int wv   = threadIdx.x >> 6;
    const int rr   = blockIdx.y;

    const short8* wp = reinterpret_cast<const short8*>(wpack);
    const short8* hp = reinterpret_cast<const short8*>(hpack);

    short8 X[8][4];
    #pragma unroll
    for (int fb = 0; fb < 8; ++fb)
        #pragma unroll
        for (int ks = 0; ks < 4; ++ks)
            X[fb][ks] = wp[(((rr * 8 + fb) * 4 + ks) << 6) + lane];

    const int wgid    = blockIdx.x * 4 + wv;
    const int wstride = gridDim.x * 4;

    for (int mb = wgid; mb < nmblk; mb += wstride) {
        short8 Y[4];
        #pragma unroll
        for (int ks = 0; ks < 4; ++ks)
            Y[ks] = hp[((mb * 4 + ks) << 6) + lane];

        f32x4 acc[8];
        #pragma unroll
        for (int fb = 0; fb < 8; ++fb) acc[fb] = f32x4{0.f, 0.f, 0.f, 0.f};

        #pragma unroll
        for (int ks = 0; ks < 4; ++ks)
            #pragma unroll
            for (int fb = 0; fb < 8; ++fb)
                acc[fb] = __builtin_amdgcn_mfma_f32_16x16x32_bf16(X[fb][ks], Y[ks], acc[fb], 0, 0, 0);

        const int node = mb * 16 + (lane & 15);
        if (node < n_nodes) {
            ushort* prow = proj + ((size_t)rr * n_nodes + node) * FEAT + (lane >> 4) * 4;
            #pragma unroll
            for (int fb = 0; fb < 8; ++fb) {
                unsigned d0 = (unsigned)f2bf(acc[fb][0]) | ((unsigned)f2bf(acc[fb][1]) << 16);
                unsigned d1 = (unsigned)f2bf(acc[fb][2]) | ((unsigned)f2bf(acc[fb][3]) << 16);
                uint2 d; d.x = d0; d.y = d1;
                *reinterpret_cast<uint2*>(prow + fb * 16) = d;
            }
        }
    }
}

// ---------------------------------------------------------------------------
// Bucket histogram: gcnt[b] = #edges with dst>>5 == b  (LDS-staged, int atomics)
// ---------------------------------------------------------------------------
__global__ __launch_bounds__(256) void bhist_kernel(
    const int* __restrict__ dst, int* __restrict__ gcnt, int n_edges, int nbkt)
{
    __shared__ int cnt[1024];
    for (int i = threadIdx.x; i < nbkt; i += 256) cnt[i] = 0;
    __syncthreads();
    int i = blockIdx.x * 256 + threadIdx.x;
    int stride = gridDim.x * 256;
    for (; i < n_edges; i += stride)
        atomicAdd(&cnt[dst[i] >> 5], 1);
    __syncthreads();
    for (int i2 = threadIdx.x; i2 < nbkt; i2 += 256)
        if (cnt[i2] > 0) atomicAdd(&gcnt[i2], cnt[i2]);
}

// ---------------------------------------------------------------------------
// Scan over nbkt (<=1024) bins -> boffs[nbkt+1], gcur copy
// ---------------------------------------------------------------------------
__global__ __launch_bounds__(1024) void bscan_kernel(
    const int* __restrict__ gcnt, int* __restrict__ boffs,
    int* __restrict__ gcur, int nbkt)
{
    __shared__ int part[1024];
    const int tid = threadIdx.x;
    part[tid] = (tid < nbkt) ? gcnt[tid] : 0;
    __syncthreads();
    for (int d = 1; d < 1024; d <<= 1) {
        int v = (tid >= d) ? part[tid - d] : 0;
        __syncthreads();
        part[tid] += v;
        __syncthreads();
    }
    int excl = (tid > 0) ? part[tid - 1] : 0;
    if (tid < nbkt) { boffs[tid] = excl; gcur[tid] = excl; }
    if (tid == 1023) boffs[nbkt] = part[1023];
}

// ---------------------------------------------------------------------------
// Partition: LDS-staged two-pass scatter -> recs_tmp grouped by bucket.
// rec.x = src | rel<<15 | (dst&31)<<19 ; rec.y = norm bits
// ---------------------------------------------------------------------------
__global__ __launch_bounds__(256) void partition_kernel(
    const int* __restrict__ src, const int* __restrict__ dst,
    const int* __restrict__ rel, const float* __restrict__ norm,
    int* __restrict__ gcur, uint2* __restrict__ recs_tmp, int n_edges, int nbkt)
{
    __shared__ int cnt[1024];
    __shared__ int base[1024];
    __shared__ int cur[1024];
    __shared__ uint2 stage[PCHUNK];
    __shared__ ushort sbkt[PCHUNK];

    const int tid = threadIdx.x;
    const int c0 = blockIdx.x * PCHUNK;

    for (int i = tid; i < nbkt; i += 256) { cnt[i] = 0; cur[i] = 0; }
    __syncthreads();

    #pragma unroll
    for (int j = 0; j < PCHUNK / 256; ++j) {
        int slot = j * 256 + tid;
        int e = c0 + slot;
        if (e < n_edges) {
            int d = dst[e];
            int b = d >> 5;
            uint2 r;
            r.x = (unsigned)src[e] | ((unsigned)rel[e] << 15) | ((unsigned)(d & 31) << 19);
            r.y = __float_as_uint(norm[e]);
            stage[slot] = r;
            sbkt[slot] = (ushort)b;
            atomicAdd(&cnt[b], 1);
        } else {
            sbkt[slot] = 0xffffu;
        }
    }
    __syncthreads();

    for (int i = tid; i < nbkt; i += 256)
        if (cnt[i] > 0) base[i] = atomicAdd(&gcur[i], cnt[i]);
    __syncthreads();

    #pragma unroll
    for (int j = 0; j < PCHUNK / 256; ++j) {
        int slot = j * 256 + tid;
        ushort b = sbkt[slot];
        if (b != 0xffffu) {
            int rank = atomicAdd(&cur[b], 1);
            recs_tmp[base[b] + rank] = stage[slot];
        }
    }
}

// ---------------------------------------------------------------------------
// bsort: one block per bucket. Two passes over the bucket's records with
// int LDS counters/cursors -> node-sorted recs + per-node CSR offs.
// ---------------------------------------------------------------------------
__global__ __launch_bounds__(256) void bsort_kernel(
    const uint2* __restrict__ recs_tmp, const int* __restrict__ boffs,
    uint2* __restrict__ recs, int* __restrict__ offs,
    int n_nodes, int n_edges, int nbkt)
{
    __shared__ int cnt[BKT_SZ];
    __shared__ int cur[BKT_SZ];
    const int b = blockIdx.x;
    const int tid = threadIdx.x;
    const int beg = boffs[b], end = boffs[b + 1];

    if (tid < BKT_SZ) cnt[tid] = 0;
    __syncthreads();
    for (int i = beg + tid; i < end; i += 256)
        atomicAdd(&cnt[(recs_tmp[i].x >> 19) & 31u], 1);
    __syncthreads();
    if (tid == 0) {
        int run = beg;
        for (int k = 0; k < BKT_SZ; ++k) {
            int node = b * BKT_SZ + k;
            if (node < n_nodes) offs[node] = run;
            cur[k] = run;
            run += cnt[k];
        }
        if (b == nbkt - 1) offs[n_nodes] = n_edges;
    }
    __syncthreads();
    for (int i = beg + tid; i < end; i += 256) {
        uint2 r = recs_tmp[i];
        int p = atomicAdd(&cur[(r.x >> 19) & 31u], 1);
        recs[p] = r;
    }
}

// ---------------------------------------------------------------------------
// gather4: 4 nodes per wave (16 lanes x 16B = full 256B proj row per group).
// Register accumulation, 1-deep prefetch, fused ReLU, float4 stores.
// ---------------------------------------------------------------------------
__global__ __launch_bounds__(256) void gather4_kernel(
    const ushort* __restrict__ proj, const uint2* __restrict__ recs,
    const int* __restrict__ offs, float* __restrict__ out,
    int n_nodes, int n_edges)
{
    const int wid  = (int)((blockIdx.x * blockDim.x + threadIdx.x) >> 6);
    const int lane = threadIdx.x & 63;
    const int sl   = lane & 15;
    const int node = wid * 4 + (lane >> 4);
    if (node >= n_nodes) return;

    const int beg = offs[node];
    const int end = offs[node + 1];
    const int gbase = lane & 48;          // first lane of my 16-lane group

    float a0 = 0.f, a1 = 0.f, a2 = 0.f, a3 = 0.f;
    float a4 = 0.f, a5 = 0.f, a6 = 0.f, a7 = 0.f;

    for (int base = beg; base < end; base += 16) {
        int n = end - base; if (n > 16) n = 16;
        int idx = base + sl; if (idx >= end) idx = end - 1;
        uint2 r = recs[idx];

        // j = 0
        unsigned key = (unsigned)__shfl((int)r.x, gbase);
        float    nm  = __uint_as_float((unsigned)__shfl((int)r.y, gbase));
        const ushort* prow = proj +
            ((size_t)((key >> 15) & 0xfu) * n_nodes + (key & 0x7fffu)) * FEAT + sl * 8;
        uint4 v = *reinterpret_cast<const uint4*>(prow);

        for (int j = 0; j < n; ++j) {
            uint4 vc = v; float nmc = nm;
            if (j + 1 < n) {
                unsigned key2 = (unsigned)__shfl((int)r.x, gbase + j + 1);
                nm = __uint_as_float((unsigned)__shfl((int)r.y, gbase + j + 1));
                const ushort* prow2 = proj +
                    ((size_t)((key2 >> 15) & 0xfu) * n_nodes + (key2 & 0x7fffu)) * FEAT + sl * 8;
                v = *reinterpret_cast<const uint4*>(prow2);
            }
            a0 += bf2f((ushort)(vc.x & 0xffffu)) * nmc;
            a1 += bf2f((ushort)(vc.x >> 16)) * nmc;
            a2 += bf2f((ushort)(vc.y & 0xffffu)) * nmc;
            a3 += bf2f((ushort)(vc.y >> 16)) * nmc;
            a4 += bf2f((ushort)(vc.z & 0xffffu)) * nmc;
            a5 += bf2f((ushort)(vc.z >> 16)) * nmc;
            a6 += bf2f((ushort)(vc.w & 0xffffu)) * nmc;
            a7 += bf2f((ushort)(vc.w >> 16)) * nmc;
        }
    }

    float* o = out + (size_t)node * FEAT + sl * 8;
    float4 o0, o1;
    o0.x = fmaxf(a0, 0.f); o0.y = fmaxf(a1, 0.f);
    o0.z = fmaxf(a2, 0.f); o0.w = fmaxf(a3, 0.f);
    o1.x = fmaxf(a4, 0.f); o1.y = fmaxf(a5, 0.f);
    o1.z = fmaxf(a6, 0.f); o1.w = fmaxf(a7, 0.f);
    *reinterpret_cast<float4*>(o)     = o0;
    *reinterpret_cast<float4*>(o + 4) = o1;
}

// ---------------------------------------------------------------------------
// Fallback (small ws): LDS proj + atomic edge path
// ---------------------------------------------------------------------------
constexpr int BM = 64;

__global__ __launch_bounds__(256) void proj_kernel(
    const float* __restrict__ h, const float* __restrict__ W,
    ushort* __restrict__ proj, int n_nodes, int r0)
{
    __shared__ ushort Wt[128][136];
    __shared__ ushort hs[BM][136];

    const int tid  = threadIdx.x;
    const int rel  = r0 + blockIdx.y;
    const float* Wg = W + (size_t)rel * FEAT * FEAT;

    #pragma unroll
    for (int it = 0; it < 16; ++it) {
        int f = (it * 256 + tid) * 4;
        int k = f >> 7, n = f & 127;
        float4 w4 = *reinterpret_cast<const float4*>(Wg + f);
        Wt[n + 0][k] = f2bf(w4.x);
        Wt[n + 1][k] = f2bf(w4.y);
        Wt[n + 2][k] = f2bf(w4.z);
        Wt[n + 3][k] = f2bf(w4.w);
    }

    const int lane = tid & 63;
    const int wave = tid >> 6;
    const int r    = lane & 15;
    const int kgrp = lane >> 4;

    ushort* projr = proj + (size_t)blockIdx.y * n_nodes * FEAT;
    const int nchunks = (n_nodes + BM - 1) / BM;

    for (int c = blockIdx.x; c < nchunks; c += gridDim.x) {
        const int m0 = c * BM;
        __syncthreads();
        #pragma unroll
        for (int it = 0; it < 8; ++it) {
            int f = (it * 256 + tid) * 4;
            int m = f >> 7, k = f & 127;
            int row = m0 + m;
            float4 v = make_float4(0.f, 0.f, 0.f, 0.f);
            if (row < n_nodes)
                v = *reinterpret_cast<const float4*>(h + (size_t)row * FEAT + k);
            ushort4 u;
            u.x = f2bf(v.x); u.y = f2bf(v.y); u.z = f2bf(v.z); u.w = f2bf(v.w);
            *reinterpret_cast<ushort4*>(&hs[m][k]) = u;
        }
        __syncthreads();

        f32x4 acc[8];
        #pragma unroll
        for (int i = 0; i < 8; ++i) acc[i] = f32x4{0.f, 0.f, 0.f, 0.f};

        #pragma unroll
        for (int kk = 0; kk < 4; ++kk) {
            const int kbase = kk * 32 + kgrp * 8;
            short8 a = *reinterpret_cast<const short8*>(&hs[wave * 16 + r][kbase]);
            #pragma unroll
            for (int ct = 0; ct < 8; ++ct) {
                short8 b = *reinterpret_cast<const short8*>(&Wt[ct * 16 + r][kbase]);
                acc[ct] = __builtin_amdgcn_mfma_f32_16x16x32_bf16(a, b, acc[ct], 0, 0, 0);
            }
        }

        #pragma unroll
        for (int ct = 0; ct < 8; ++ct) {
            #pragma unroll
            for (int i = 0; i < 4; ++i) {
                int row = m0 + wave * 16 + kgrp * 4 + i;
                if (row < n_nodes)
                    projr[(size_t)row * FEAT + ct * 16 + r] = f2bf(acc[ct][i]);
            }
        }
    }
}

__global__ __launch_bounds__(256) void edge_kernel(
    const ushort* __restrict__ proj, const float* __restrict__ norm,
    const int* __restrict__ src, const int* __restrict__ dst,
    const int* __restrict__ rel, float* __restrict__ out,
    int n_edges, int n_nodes, int r0, int r1)
{
    const int lane = threadIdx.x & 63;
    int gw = (int)((blockIdx.x * blockDim.x + threadIdx.x) >> 6);
    const int nw = (int)((gridDim.x * blockDim.x) >> 6);

    for (int e = gw; e < n_edges; e += nw) {
        int rr = rel[e];
        if (rr < r0 || rr >= r1) continue;
        int s = src[e];
        int d = dst[e];
        float nm = norm[e];
        const ushort* prow = proj + ((size_t)(rr - r0) * n_nodes + s) * FEAT;
        unsigned int v = *reinterpret_cast<const unsigned int*>(prow + lane * 2);
        float x0 = bf2f((ushort)(v & 0xffffu)) * nm;
        float x1 = bf2f((ushort)(v >> 16)) * nm;
        float* o = out + (size_t)d * FEAT + lane * 2;
        atomicAdd(o + 0, x0);
        atomicAdd(o + 1, x1);
    }
}

__global__ __launch_bounds__(256) void relu_kernel(float4* out, int n4)
{
    int i = blockIdx.x * blockDim.x + threadIdx.x;
    int stride = gridDim.x * blockDim.x;
    for (; i < n4; i += stride) {
        float4 v = out[i];
        v.x = fmaxf(v.x, 0.f);
        v.y = fmaxf(v.y, 0.f);
        v.z = fmaxf(v.z, 0.f);
        v.w = fmaxf(v.w, 0.f);
        out[i] = v;
    }
}

extern "C" void kernel_launch(void* const* d_in, const int* in_sizes, int n_in,
                              void* d_out, int out_size, void* d_ws, size_t ws_size,
                              hipStream_t stream)
{
    const float* h    = (const float*)d_in[0];
    const float* W    = (const float*)d_in[1];
    const float* norm = (const float*)d_in[2];
    const int*   src  = (const int*)d_in[3];
    const int*   dst  = (const int*)d_in[4];
    const int*   rel  = (const int*)d_in[5];
    float* out = (float*)d_out;

    const int n_nodes = in_sizes[0] / FEAT;   // 20000
    const int n_edges = in_sizes[3];          // 640000
    const int nmblk   = (n_nodes + 15) / 16;
    const int nbkt    = (n_nodes + BKT_SZ - 1) / BKT_SZ;   // 625

    // ws layout
    const size_t projB    = (size_t)NRELS * n_nodes * FEAT * sizeof(ushort);
    const size_t rtmpOff  = (projB + 255) & ~(size_t)255;
    const size_t recsB    = (size_t)n_edges * sizeof(uint2);
    const size_t recsOff  = (rtmpOff + recsB + 255) & ~(size_t)255;
    const size_t gcntOff  = (recsOff + recsB + 255) & ~(size_t)255;
    const size_t bktB     = ((size_t)(nbkt + 1) * 4 + 255) & ~(size_t)255;
    const size_t boffOff  = gcntOff + bktB;
    const size_t gcurOff  = boffOff + bktB;
    const size_t offsOff  = gcurOff + bktB;
    const size_t offsB    = ((size_t)(n_nodes + 1) * 4 + 255) & ~(size_t)255;
    const size_t hpackOff = offsOff + offsB;
    const size_t hpackB   = ((size_t)nmblk * 256 * 8 * sizeof(ushort) + 255) & ~(size_t)255;
    const size_t wpackOff = hpackOff + hpackB;
    const size_t wpackB   = (size_t)NRELS * 8 * 4 * 64 * 8 * sizeof(ushort);
    const size_t need     = wpackOff + wpackB;

    if (ws_size >= need && n_nodes < 32768 && nbkt <= 1024) {
        ushort* proj   = (ushort*)d_ws;
        uint2*  rtmp   = (uint2*)((char*)d_ws + rtmpOff);
        uint2*  recs   = (uint2*)((char*)d_ws + recsOff);
        int*    gcnt   = (int*)((char*)d_ws + gcntOff);
        int*    boffs  = (int*)((char*)d_ws + boffOff);
        int*    gcur   = (int*)((char*)d_ws + gcurOff);
        int*    offs   = (int*)((char*)d_ws + offsOff);
        ushort* hpack  = (ushort*)((char*)d_ws + hpackOff);
        ushort* wpack  = (ushort*)((char*)d_ws + wpackOff);

        pack_h_kernel<<<nmblk, 256, 0, stream>>>(h, hpack, n_nodes, nmblk);
        pack_w_kernel<<<(NRELS * 8 * 4 * 64 + 255) / 256, 256, 0, stream>>>(W, wpack);
        dim3 g1(128, NRELS);
        proj2_kernel<<<g1, 256, 0, stream>>>(hpack, wpack, proj, n_nodes, nmblk);

        hipMemsetAsync(gcnt, 0, (size_t)(nbkt + 1) * 4, stream);
        bhist_kernel<<<256, 256, 0, stream>>>(dst, gcnt, n_edges, nbkt);
        bscan_kernel<<<1, 1024, 0, stream>>>(gcnt, boffs, gcur, nbkt);
        partition_kernel<<<(n_edges + PCHUNK - 1) / PCHUNK, 256, 0, stream>>>(
            src, dst, rel, norm, gcur, rtmp, n_edges, nbkt);
        bsort_kernel<<<nbkt, 256, 0, stream>>>(rtmp, boffs, recs, offs,
                                               n_nodes, n_edges, nbkt);

        const int nwaves = (n_nodes + 3) / 4;
        gather4_kernel<<<(nwaves * 64 + 255) / 256, 256, 0, stream>>>(
            proj, recs, offs, out, n_nodes, n_edges);
    } else {
        // fallback: relation-chunked atomic path
        ushort* proj = (ushort*)d_ws;
        hipMemsetAsync(out, 0, (size_t)out_size * sizeof(float), stream);
        const size_t perRel = (size_t)n_nodes * FEAT * sizeof(ushort);
        int rc = (int)(ws_size / perRel);
        if (rc < 1) rc = 1;
        if (rc > NRELS) rc = NRELS;
        for (int r0 = 0; r0 < NRELS; r0 += rc) {
            const int rcc = (rc < NRELS - r0) ? rc : (NRELS - r0);
            dim3 g1(32, rcc);
            proj_kernel<<<g1, 256, 0, stream>>>(h, W, proj, n_nodes, r0);
            edge_kernel<<<1024, 256, 0, stream>>>(proj, norm, src, dst, rel, out,
                                                  n_edges, n_nodes, r0, r0 + rcc);
        }
        relu_kernel<<<2048, 256, 0, stream>>>((float4*)out, out_size / 4);
    }
}

// Round 7
// 108.887 us; speedup vs baseline: 5.4934x; 1.0752x over previous
//
#include <hip/hip_runtime.h>
#include <hip/hip_bf16.h>

#define FEAT 128
#define NRELS 16
#define BKT_SZ 32          // dst nodes per bucket
#define PCHUNK 4096        // edges per partition block (16 per thread)

using short8 = __attribute__((ext_vector_type(8))) short;
using f32x4  = __attribute__((ext_vector_type(4))) float;

__device__ inline ushort f2bf(float x) {
    union { float f; unsigned int u; } v; v.f = x;
    unsigned int u = v.u;
    unsigned int r = (u + 0x7fffu + ((u >> 16) & 1u)) >> 16;  // RNE
    return (ushort)r;
}
__device__ inline float bf2f(ushort b) {
    union { unsigned int u; float f; } v; v.u = ((unsigned int)b) << 16;
    return v.f;
}

// ---------------------------------------------------------------------------
// zero_kernel: replaces hipMemsetAsync (rocclr fillBuffer cost 40us/replay!)
// ---------------------------------------------------------------------------
__global__ __launch_bounds__(256) void zero_kernel(int* __restrict__ p, int n)
{
    int i = blockIdx.x * 256 + threadIdx.x;
    if (i < n) p[i] = 0;
}

// ---------------------------------------------------------------------------
// Pack h -> bf16 MFMA A-slabs:
//   hpack[(mblk*4+ks)*64 + lane][j] = h[mblk*16 + (lane&15)][ks*32 + (lane>>4)*8 + j]
// ---------------------------------------------------------------------------
__global__ __launch_bounds__(256) void pack_h_kernel(
    const float* __restrict__ h, ushort* __restrict__ hpack, int n_nodes, int nmblk)
{
    int t = blockIdx.x * 256 + threadIdx.x;
    if (t >= nmblk * 256) return;
    int lane = t & 63;
    int mblk = t >> 8;
    int ks   = (t >> 6) & 3;
    int row  = mblk * 16 + (lane & 15);
    int k0   = ks * 32 + (lane >> 4) * 8;

    ushort u[8] = {0, 0, 0, 0, 0, 0, 0, 0};
    if (row < n_nodes) {
        const float* p = h + (size_t)row * FEAT + k0;
        float4 a = *reinterpret_cast<const float4*>(p);
        float4 b = *reinterpret_cast<const float4*>(p + 4);
        u[0] = f2bf(a.x); u[1] = f2bf(a.y); u[2] = f2bf(a.z); u[3] = f2bf(a.w);
        u[4] = f2bf(b.x); u[5] = f2bf(b.y); u[6] = f2bf(b.z); u[7] = f2bf(b.w);
    }
    *reinterpret_cast<short8*>(hpack + (size_t)t * 8) = *reinterpret_cast<short8*>(u);
}

// ---------------------------------------------------------------------------
// Pack W^T -> bf16 MFMA slabs (slab row index = output feature):
//   wpack[((r*8+fb)*4+ks)*64 + lane][j] = W[r][ks*32+(lane>>4)*8+j][fb*16+(lane&15)]
// ---------------------------------------------------------------------------
__global__ __launch_bounds__(256) void pack_w_kernel(
    const float* __restrict__ W, ushort* __restrict__ wpack)
{
    int t = blockIdx.x * 256 + threadIdx.x;
    if (t >= NRELS * 8 * 4 * 64) return;
    int lane = t & 63;
    int ks   = (t >> 6) & 3;
    int fb   = (t >> 8) & 7;
    int r    = t >> 11;
    int k0   = ks * 32 + (lane >> 4) * 8;
    int f    = fb * 16 + (lane & 15);

    ushort u[8];
    #pragma unroll
    for (int j = 0; j < 8; ++j)
        u[j] = f2bf(W[((size_t)r * FEAT + (k0 + j)) * FEAT + f]);
    *reinterpret_cast<short8*>(wpack + (size_t)t * 8) = *reinterpret_cast<short8*>(u);
}

// ---------------------------------------------------------------------------
// proj[r][n][f] = h[n][:] @ W[r][:][f]
// D = mfma(Wfrag, hfrag): node = lane&15, feat = fb*16 + (lane>>4)*4 + i
// Epilogue: stage 16x128 bf16 tile per wave in padded LDS, then store full
// 256B rows (16B/lane, fully coalesced). Block-uniform loop so that
// __syncthreads() (compiler-visible fence) can order the LDS exchange —
// an inline-asm lgkmcnt alone is NOT a scheduling fence (R6 failure).
// ---------------------------------------------------------------------------
__global__ __launch_bounds__(256) void proj2_kernel(
    const ushort* __restrict__ hpack, const ushort* __restrict__ wpack,
    ushort* __restrict__ proj, int n_nodes, int nmblk)
{
    __shared__ ushort stg[4][16][136];   // per-wave 16x128 tile, +8 pad

    const int lane = threadIdx.x & 63;
    const int wv   = threadIdx.x >> 6;
    const int rr   = blockIdx.y;

    const short8* wp = reinterpret_cast<const short8*>(wpack);
    const short8* hp = reinterpret_cast<const short8*>(hpack);

    short8 X[8][4];
    #pragma unroll
    for (int fb = 0; fb < 8; ++fb)
        #pragma unroll
        for (int ks = 0; ks < 4; ++ks)
            X[fb][ks] = wp[(((rr * 8 + fb) * 4 + ks) << 6) + lane];

    const int niter = (nmblk + 3) / 4;   // block-uniform trip count

    for (int it = blockIdx.x; it < niter; it += gridDim.x) {
        const int mb = it * 4 + wv;
        const bool active = (mb < nmblk);

        f32x4 acc[8];
        #pragma unroll
        for (int fb = 0; fb < 8; ++fb) acc[fb] = f32x4{0.f, 0.f, 0.f, 0.f};

        if (active) {
            short8 Y[4];
            #pragma unroll
            for (int ks = 0; ks < 4; ++ks)
                Y[ks] = hp[((mb * 4 + ks) << 6) + lane];

            #pragma unroll
            for (int ks = 0; ks < 4; ++ks)
                #pragma unroll
                for (int fb = 0; fb < 8; ++fb)
                    acc[fb] = __builtin_amdgcn_mfma_f32_16x16x32_bf16(X[fb][ks], Y[ks], acc[fb], 0, 0, 0);
        }

        __syncthreads();   // previous iteration's reads done before rewrite

        if (active) {
            ushort (*S)[136] = stg[wv];
            #pragma unroll
            for (int fb = 0; fb < 8; ++fb) {
                uint2 d;
                d.x = (unsigned)f2bf(acc[fb][0]) | ((unsigned)f2bf(acc[fb][1]) << 16);
                d.y = (unsigned)f2bf(acc[fb][2]) | ((unsigned)f2bf(acc[fb][3]) << 16);
                *reinterpret_cast<uint2*>(&S[lane & 15][fb * 16 + (lane >> 4) * 4]) = d;
            }
        }

        __syncthreads();   // writes visible before cross-lane reads

        if (active) {
            ushort (*S)[136] = stg[wv];
            #pragma unroll
            for (int i = 0; i < 4; ++i) {
                const int row  = i * 4 + (lane >> 4);
                const int node = mb * 16 + row;
                if (node < n_nodes) {
                    uint4 v = *reinterpret_cast<const uint4*>(&S[row][(lane & 15) * 8]);
                    *reinterpret_cast<uint4*>(
                        proj + ((size_t)rr * n_nodes + node) * FEAT + (lane & 15) * 8) = v;
                }
            }
        }
    }
}

// ---------------------------------------------------------------------------
// Bucket histogram: gcnt[b] = #edges with dst>>5 == b  (LDS-staged, int atomics)
// ---------------------------------------------------------------------------
__global__ __launch_bounds__(256) void bhist_kernel(
    const int* __restrict__ dst, int* __restrict__ gcnt, int n_edges, int nbkt)
{
    __shared__ int cnt[1024];
    for (int i = threadIdx.x; i < nbkt; i += 256) cnt[i] = 0;
    __syncthreads();
    int i = blockIdx.x * 256 + threadIdx.x;
    int stride = gridDim.x * 256;
    for (; i < n_edges; i += stride)
        atomicAdd(&cnt[dst[i] >> 5], 1);
    __syncthreads();
    for (int i2 = threadIdx.x; i2 < nbkt; i2 += 256)
        if (cnt[i2] > 0) atomicAdd(&gcnt[i2], cnt[i2]);
}

// ---------------------------------------------------------------------------
// Scan over nbkt (<=1024) bins -> boffs[nbkt+1], gcur copy
// ---------------------------------------------------------------------------
__global__ __launch_bounds__(1024) void bscan_kernel(
    const int* __restrict__ gcnt, int* __restrict__ boffs,
    int* __restrict__ gcur, int nbkt)
{
    __shared__ int part[1024];
    const int tid = threadIdx.x;
    part[tid] = (tid < nbkt) ? gcnt[tid] : 0;
    __syncthreads();
    for (int d = 1; d < 1024; d <<= 1) {
        int v = (tid >= d) ? part[tid - d] : 0;
        __syncthreads();
        part[tid] += v;
        __syncthreads();
    }
    int excl = (tid > 0) ? part[tid - 1] : 0;
    if (tid < nbkt) { boffs[tid] = excl; gcur[tid] = excl; }
    if (tid == 1023) boffs[nbkt] = part[1023];
}

// ---------------------------------------------------------------------------
// Partition: LDS-staged two-pass scatter -> recs_tmp grouped by bucket.
// rec.x = src | rel<<15 | (dst&31)<<19 ; rec.y = norm bits
// ---------------------------------------------------------------------------
__global__ __launch_bounds__(256) void partition_kernel(
    const int* __restrict__ src, const int* __restrict__ dst,
    const int* __restrict__ rel, const float* __restrict__ norm,
    int* __restrict__ gcur, uint2* __restrict__ recs_tmp, int n_edges, int nbkt)
{
    __shared__ int cnt[1024];
    __shared__ int base[1024];
    __shared__ int cur[1024];
    __shared__ uint2 stage[PCHUNK];
    __shared__ ushort sbkt[PCHUNK];

    const int tid = threadIdx.x;
    const int c0 = blockIdx.x * PCHUNK;

    for (int i = tid; i < nbkt; i += 256) { cnt[i] = 0; cur[i] = 0; }
    __syncthreads();

    #pragma unroll
    for (int j = 0; j < PCHUNK / 256; ++j) {
        int slot = j * 256 + tid;
        int e = c0 + slot;
        if (e < n_edges) {
            int d = dst[e];
            int b = d >> 5;
            uint2 r;
            r.x = (unsigned)src[e] | ((unsigned)rel[e] << 15) | ((unsigned)(d & 31) << 19);
            r.y = __float_as_uint(norm[e]);
            stage[slot] = r;
            sbkt[slot] = (ushort)b;
            atomicAdd(&cnt[b], 1);
        } else {
            sbkt[slot] = 0xffffu;
        }
    }
    __syncthreads();

    for (int i = tid; i < nbkt; i += 256)
        if (cnt[i] > 0) base[i] = atomicAdd(&gcur[i], cnt[i]);
    __syncthreads();

    #pragma unroll
    for (int j = 0; j < PCHUNK / 256; ++j) {
        int slot = j * 256 + tid;
        ushort b = sbkt[slot];
        if (b != 0xffffu) {
            int rank = atomicAdd(&cur[b], 1);
            recs_tmp[base[b] + rank] = stage[slot];
        }
    }
}

// ---------------------------------------------------------------------------
// bsort: one block per bucket. Two passes over the bucket's records with
// int LDS counters/cursors -> node-sorted recs + per-node CSR offs.
// ---------------------------------------------------------------------------
__global__ __launch_bounds__(256) void bsort_kernel(
    const uint2* __restrict__ recs_tmp, const int* __restrict__ boffs,
    uint2* __restrict__ recs, int* __restrict__ offs,
    int n_nodes, int n_edges, int nbkt)
{
    __shared__ int cnt[BKT_SZ];
    __shared__ int cur[BKT_SZ];
    const int b = blockIdx.x;
    const int tid = threadIdx.x;
    const int beg = boffs[b], end = boffs[b + 1];

    if (tid < BKT_SZ) cnt[tid] = 0;
    __syncthreads();
    for (int i = beg + tid; i < end; i += 256)
        atomicAdd(&cnt[(recs_tmp[i].x >> 19) & 31u], 1);
    __syncthreads();
    if (tid == 0) {
        int run = beg;
        for (int k = 0; k < BKT_SZ; ++k) {
            int node = b * BKT_SZ + k;
            if (node < n_nodes) offs[node] = run;
            cur[k] = run;
            run += cnt[k];
        }
        if (b == nbkt - 1) offs[n_nodes] = n_edges;
    }
    __syncthreads();
    for (int i = beg + tid; i < end; i += 256) {
        uint2 r = recs_tmp[i];
        int p = atomicAdd(&cur[(r.x >> 19) & 31u], 1);
        recs[p] = r;
    }
}

// ---------------------------------------------------------------------------
// gather4: 4 nodes per wave (16 lanes x 16B = full 256B proj row per group).
// Register accumulation, 1-deep prefetch, fused ReLU, float4 stores.
// ---------------------------------------------------------------------------
__global__ __launch_bounds__(256) void gather4_kernel(
    const ushort* __restrict__ proj, const uint2* __restrict__ recs,
    const int* __restrict__ offs, float* __restrict__ out,
    int n_nodes, int n_edges)
{
    const int wid  = (int)((blockIdx.x * blockDim.x + threadIdx.x) >> 6);
    const int lane = threadIdx.x & 63;
    const int sl   = lane & 15;
    const int node = wid * 4 + (lane >> 4);
    if (node >= n_nodes) return;

    const int beg = offs[node];
    const int end = offs[node + 1];
    const int gbase = lane & 48;          // first lane of my 16-lane group

    float a0 = 0.f, a1 = 0.f, a2 = 0.f, a3 = 0.f;
    float a4 = 0.f, a5 = 0.f, a6 = 0.f, a7 = 0.f;

    for (int base = beg; base < end; base += 16) {
        int n = end - base; if (n > 16) n = 16;
        int idx = base + sl; if (idx >= end) idx = end - 1;
        uint2 r = recs[idx];

        // j = 0
        unsigned key = (unsigned)__shfl((int)r.x, gbase);
        float    nm  = __uint_as_float((unsigned)__shfl((int)r.y, gbase));
        const ushort* prow = proj +
            ((size_t)((key >> 15) & 0xfu) * n_nodes + (key & 0x7fffu)) * FEAT + sl * 8;
        uint4 v = *reinterpret_cast<const uint4*>(prow);

        for (int j = 0; j < n; ++j) {
            uint4 vc = v; float nmc = nm;
            if (j + 1 < n) {
                unsigned key2 = (unsigned)__shfl((int)r.x, gbase + j + 1);
                nm = __uint_as_float((unsigned)__shfl((int)r.y, gbase + j + 1));
                const ushort* prow2 = proj +
                    ((size_t)((key2 >> 15) & 0xfu) * n_nodes + (key2 & 0x7fffu)) * FEAT + sl * 8;
                v = *reinterpret_cast<const uint4*>(prow2);
            }
            a0 += bf2f((ushort)(vc.x & 0xffffu)) * nmc;
            a1 += bf2f((ushort)(vc.x >> 16)) * nmc;
            a2 += bf2f((ushort)(vc.y & 0xffffu)) * nmc;
            a3 += bf2f((ushort)(vc.y >> 16)) * nmc;
            a4 += bf2f((ushort)(vc.z & 0xffffu)) * nmc;
            a5 += bf2f((ushort)(vc.z >> 16)) * nmc;
            a6 += bf2f((ushort)(vc.w & 0xffffu)) * nmc;
            a7 += bf2f((ushort)(vc.w >> 16)) * nmc;
        }
    }

    float* o = out + (size_t)node * FEAT + sl * 8;
    float4 o0, o1;
    o0.x = fmaxf(a0, 0.f); o0.y = fmaxf(a1, 0.f);
    o0.z = fmaxf(a2, 0.f); o0.w = fmaxf(a3, 0.f);
    o1.x = fmaxf(a4, 0.f); o1.y = fmaxf(a5, 0.f);
    o1.z = fmaxf(a6, 0.f); o1.w = fmaxf(a7, 0.f);
    *reinterpret_cast<float4*>(o)     = o0;
    *reinterpret_cast<float4*>(o + 4) = o1;
}

// ---------------------------------------------------------------------------
// Fallback (small ws): LDS proj + atomic edge path
// ---------------------------------------------------------------------------
constexpr int BM = 64;

__global__ __launch_bounds__(256) void proj_kernel(
    const float* __restrict__ h, const float* __restrict__ W,
    ushort* __restrict__ proj, int n_nodes, int r0)
{
    __shared__ ushort Wt[128][136];
    __shared__ ushort hs[BM][136];

    const int tid  = threadIdx.x;
    const int rel  = r0 + blockIdx.y;
    const float* Wg = W + (size_t)rel * FEAT * FEAT;

    #pragma unroll
    for (int it = 0; it < 16; ++it) {
        int f = (it * 256 + tid) * 4;
        int k = f >> 7, n = f & 127;
        float4 w4 = *reinterpret_cast<const float4*>(Wg + f);
        Wt[n + 0][k] = f2bf(w4.x);
        Wt[n + 1][k] = f2bf(w4.y);
        Wt[n + 2][k] = f2bf(w4.z);
        Wt[n + 3][k] = f2bf(w4.w);
    }

    const int lane = tid & 63;
    const int wave = tid >> 6;
    const int r    = lane & 15;
    const int kgrp = lane >> 4;

    ushort* projr = proj + (size_t)blockIdx.y * n_nodes * FEAT;
    const int nchunks = (n_nodes + BM - 1) / BM;

    for (int c = blockIdx.x; c < nchunks; c += gridDim.x) {
        const int m0 = c * BM;
        __syncthreads();
        #pragma unroll
        for (int it = 0; it < 8; ++it) {
            int f = (it * 256 + tid) * 4;
            int m = f >> 7, k = f & 127;
            int row = m0 + m;
            float4 v = make_float4(0.f, 0.f, 0.f, 0.f);
            if (row < n_nodes)
                v = *reinterpret_cast<const float4*>(h + (size_t)row * FEAT + k);
            ushort4 u;
            u.x = f2bf(v.x); u.y = f2bf(v.y); u.z = f2bf(v.z); u.w = f2bf(v.w);
            *reinterpret_cast<ushort4*>(&hs[m][k]) = u;
        }
        __syncthreads();

        f32x4 acc[8];
        #pragma unroll
        for (int i = 0; i < 8; ++i) acc[i] = f32x4{0.f, 0.f, 0.f, 0.f};

        #pragma unroll
        for (int kk = 0; kk < 4; ++kk) {
            const int kbase = kk * 32 + kgrp * 8;
            short8 a = *reinterpret_cast<const short8*>(&hs[wave * 16 + r][kbase]);
            #pragma unroll
            for (int ct = 0; ct < 8; ++ct) {
                short8 b = *reinterpret_cast<const short8*>(&Wt[ct * 16 + r][kbase]);
                acc[ct] = __builtin_amdgcn_mfma_f32_16x16x32_bf16(a, b, acc[ct], 0, 0, 0);
            }
        }

        #pragma unroll
        for (int ct = 0; ct < 8; ++ct) {
            #pragma unroll
            for (int i = 0; i < 4; ++i) {
                int row = m0 + wave * 16 + kgrp * 4 + i;
                if (row < n_nodes)
                    projr[(size_t)row * FEAT + ct * 16 + r] = f2bf(acc[ct][i]);
            }
        }
    }
}

__global__ __launch_bounds__(256) void edge_kernel(
    const ushort* __restrict__ proj, const float* __restrict__ norm,
    const int* __restrict__ src, const int* __restrict__ dst,
    const int* __restrict__ rel, float* __restrict__ out,
    int n_edges, int n_nodes, int r0, int r1)
{
    const int lane = threadIdx.x & 63;
    int gw = (int)((blockIdx.x * blockDim.x + threadIdx.x) >> 6);
    const int nw = (int)((gridDim.x * blockDim.x) >> 6);

    for (int e = gw; e < n_edges; e += nw) {
        int rr = rel[e];
        if (rr < r0 || rr >= r1) continue;
        int s = src[e];
        int d = dst[e];
        float nm = norm[e];
        const ushort* prow = proj + ((size_t)(rr - r0) * n_nodes + s) * FEAT;
        unsigned int v = *reinterpret_cast<const unsigned int*>(prow + lane * 2);
        float x0 = bf2f((ushort)(v & 0xffffu)) * nm;
        float x1 = bf2f((ushort)(v >> 16)) * nm;
        float* o = out + (size_t)d * FEAT + lane * 2;
        atomicAdd(o + 0, x0);
        atomicAdd(o + 1, x1);
    }
}

__global__ __launch_bounds__(256) void relu_kernel(float4* out, int n4)
{
    int i = blockIdx.x * blockDim.x + threadIdx.x;
    int stride = gridDim.x * blockDim.x;
    for (; i < n4; i += stride) {
        float4 v = out[i];
        v.x = fmaxf(v.x, 0.f);
        v.y = fmaxf(v.y, 0.f);
        v.z = fmaxf(v.z, 0.f);
        v.w = fmaxf(v.w, 0.f);
        out[i] = v;
    }
}

extern "C" void kernel_launch(void* const* d_in, const int* in_sizes, int n_in,
                              void* d_out, int out_size, void* d_ws, size_t ws_size,
                              hipStream_t stream)
{
    const float* h    = (const float*)d_in[0];
    const float* W    = (const float*)d_in[1];
    const float* norm = (const float*)d_in[2];
    const int*   src  = (const int*)d_in[3];
    const int*   dst  = (const int*)d_in[4];
    const int*   rel  = (const int*)d_in[5];
    float* out = (float*)d_out;

    const int n_nodes = in_sizes[0] / FEAT;   // 20000
    const int n_edges = in_sizes[3];          // 640000
    const int nmblk   = (n_nodes + 15) / 16;
    const int nbkt    = (n_nodes + BKT_SZ - 1) / BKT_SZ;   // 625

    // ws layout
    const size_t projB    = (size_t)NRELS * n_nodes * FEAT * sizeof(ushort);
    const size_t rtmpOff  = (projB + 255) & ~(size_t)255;
    const size_t recsB    = (size_t)n_edges * sizeof(uint2);
    const size_t recsOff  = (rtmpOff + recsB + 255) & ~(size_t)255;
    const size_t gcntOff  = (recsOff + recsB + 255) & ~(size_t)255;
    const size_t bktB     = ((size_t)(nbkt + 1) * 4 + 255) & ~(size_t)255;
    const size_t boffOff  = gcntOff + bktB;
    const size_t gcurOff  = boffOff + bktB;
    const size_t offsOff  = gcurOff + bktB;
    const size_t offsB    = ((size_t)(n_nodes + 1) * 4 + 255) & ~(size_t)255;
    const size_t hpackOff = offsOff + offsB;
    const size_t hpackB   = ((size_t)nmblk * 256 * 8 * sizeof(ushort) + 255) & ~(size_t)255;
    const size_t wpackOff = hpackOff + hpackB;
    const size_t wpackB   = (size_t)NRELS * 8 * 4 * 64 * 8 * sizeof(ushort);
    const size_t need     = wpackOff + wpackB;

    if (ws_size >= need && n_nodes < 32768 && nbkt <= 1024) {
        ushort* proj   = (ushort*)d_ws;
        uint2*  rtmp   = (uint2*)((char*)d_ws + rtmpOff);
        uint2*  recs   = (uint2*)((char*)d_ws + recsOff);
        int*    gcnt   = (int*)((char*)d_ws + gcntOff);
        int*    boffs  = (int*)((char*)d_ws + boffOff);
        int*    gcur   = (int*)((char*)d_ws + gcurOff);
        int*    offs   = (int*)((char*)d_ws + offsOff);
        ushort* hpack  = (ushort*)((char*)d_ws + hpackOff);
        ushort* wpack  = (ushort*)((char*)d_ws + wpackOff);

        zero_kernel<<<(nbkt + 1 + 255) / 256, 256, 0, stream>>>(gcnt, nbkt + 1);
        pack_h_kernel<<<nmblk, 256, 0, stream>>>(h, hpack, n_nodes, nmblk);
        pack_w_kernel<<<(NRELS * 8 * 4 * 64 + 255) / 256, 256, 0, stream>>>(W, wpack);
        dim3 g1(128, NRELS);
        proj2_kernel<<<g1, 256, 0, stream>>>(hpack, wpack, proj, n_nodes, nmblk);

        bhist_kernel<<<256, 256, 0, stream>>>(dst, gcnt, n_edges, nbkt);
        bscan_kernel<<<1, 1024, 0, stream>>>(gcnt, boffs, gcur, nbkt);
        partition_kernel<<<(n_edges + PCHUNK - 1) / PCHUNK, 256, 0, stream>>>(
            src, dst, rel, norm, gcur, rtmp, n_edges, nbkt);
        bsort_kernel<<<nbkt, 256, 0, stream>>>(rtmp, boffs, recs, offs,
                                               n_nodes, n_edges, nbkt);

        const int nwaves = (n_nodes + 3) / 4;
        gather4_kernel<<<(nwaves * 64 + 255) / 256, 256, 0, stream>>>(
            proj, recs, offs, out, n_nodes, n_edges);
    } else {
        // fallback: relation-chunked atomic path
        ushort* proj = (ushort*)d_ws;
        hipMemsetAsync(out, 0, (size_t)out_size * sizeof(float), stream);
        const size_t perRel = (size_t)n_nodes * FEAT * sizeof(ushort);
        int rc = (int)(ws_size / perRel);
        if (rc < 1) rc = 1;
        if (rc > NRELS) rc = NRELS;
        for (int r0 = 0; r0 < NRELS; r0 += rc) {
            const int rcc = (rc < NRELS - r0) ? rc : (NRELS - r0);
            dim3 g1(32, rcc);
            proj_kernel<<<g1, 256, 0, stream>>>(h, W, proj, n_nodes, r0);
            edge_kernel<<<1024, 256, 0, stream>>>(proj, norm, src, dst, rel, out,
                                                  n_edges, n_nodes, r0, r0 + rcc);
        }
        relu_kernel<<<2048, 256, 0, stream>>>((float4*)out, out_size / 4);
    }
}

// Round 8
// 104.885 us; speedup vs baseline: 5.7030x; 1.0382x over previous
//
#include <hip/hip_runtime.h>
#include <hip/hip_bf16.h>

#define FEAT 128
#define NRELS 16
#define BKT_SZ 32          // dst nodes per bucket
#define PCHUNK 4096        // edges per partition block (16 per thread)
#define NHB 256            // histogram partial blocks

using short8 = __attribute__((ext_vector_type(8))) short;
using f32x4  = __attribute__((ext_vector_type(4))) float;

__device__ inline ushort f2bf(float x) {
    union { float f; unsigned int u; } v; v.f = x;
    unsigned int u = v.u;
    unsigned int r = (u + 0x7fffu + ((u >> 16) & 1u)) >> 16;  // RNE
    return (ushort)r;
}
__device__ inline float bf2f(ushort b) {
    union { unsigned int u; float f; } v; v.u = ((unsigned int)b) << 16;
    return v.f;
}

// ---------------------------------------------------------------------------
// prep: fused pack_h + pack_w + bucket-histogram-partials (role by blockIdx).
//   pack_h: hpack[(mblk*4+ks)*64+lane][j] = h[mblk*16+(lane&15)][ks*32+(lane>>4)*8+j]
//   pack_w: wpack[((r*8+fb)*4+ks)*64+lane][j] = W[r][ks*32+(lane>>4)*8+j][fb*16+(lane&15)]
//   bhist : gpart[hb*1024+bin] = partial count (non-atomic, all slots written)
// ---------------------------------------------------------------------------
__global__ __launch_bounds__(256) void prep_kernel(
    const float* __restrict__ h, const float* __restrict__ W,
    const int* __restrict__ dst,
    ushort* __restrict__ hpack, ushort* __restrict__ wpack,
    int* __restrict__ gpart,
    int n_nodes, int nmblk, int n_edges, int nbkt)
{
    const int bid = blockIdx.x;
    if (bid < nmblk) {
        // ---- pack_h ----
        int t = bid * 256 + threadIdx.x;
        int lane = t & 63;
        int mblk = t >> 8;
        int ks   = (t >> 6) & 3;
        int row  = mblk * 16 + (lane & 15);
        int k0   = ks * 32 + (lane >> 4) * 8;

        ushort u[8] = {0, 0, 0, 0, 0, 0, 0, 0};
        if (row < n_nodes) {
            const float* p = h + (size_t)row * FEAT + k0;
            float4 a = *reinterpret_cast<const float4*>(p);
            float4 b = *reinterpret_cast<const float4*>(p + 4);
            u[0] = f2bf(a.x); u[1] = f2bf(a.y); u[2] = f2bf(a.z); u[3] = f2bf(a.w);
            u[4] = f2bf(b.x); u[5] = f2bf(b.y); u[6] = f2bf(b.z); u[7] = f2bf(b.w);
        }
        *reinterpret_cast<short8*>(hpack + (size_t)t * 8) = *reinterpret_cast<short8*>(u);
    } else if (bid < nmblk + 128) {
        // ---- pack_w (128 blocks cover NRELS*8*4*64 = 32768 threads) ----
        int t = (bid - nmblk) * 256 + threadIdx.x;
        int lane = t & 63;
        int ks   = (t >> 6) & 3;
        int fb   = (t >> 8) & 7;
        int r    = t >> 11;
        int k0   = ks * 32 + (lane >> 4) * 8;
        int f    = fb * 16 + (lane & 15);

        ushort u[8];
        #pragma unroll
        for (int j = 0; j < 8; ++j)
            u[j] = f2bf(W[((size_t)r * FEAT + (k0 + j)) * FEAT + f]);
        *reinterpret_cast<short8*>(wpack + (size_t)t * 8) = *reinterpret_cast<short8*>(u);
    } else {
        // ---- bucket histogram partials ----
        const int hb = bid - nmblk - 128;     // 0..NHB-1
        __shared__ int cnt[1024];
        for (int i = threadIdx.x; i < 1024; i += 256) cnt[i] = 0;
        __syncthreads();
        for (int i = hb * 256 + threadIdx.x; i < n_edges; i += NHB * 256)
            atomicAdd(&cnt[dst[i] >> 5], 1);
        __syncthreads();
        for (int i = threadIdx.x; i < nbkt; i += 256)
            gpart[hb * 1024 + i] = cnt[i];
    }
}

// ---------------------------------------------------------------------------
// proj[r][n][f] = h[n][:] @ W[r][:][f]
// D = mfma(Wfrag, hfrag): node = lane&15, feat = fb*16 + (lane>>4)*4 + i
// Epilogue staged per-wave in padded LDS -> coalesced 256B-row stores.
// Block-uniform loop; __syncthreads() is the (compiler-visible) fence.
// ---------------------------------------------------------------------------
__global__ __launch_bounds__(256) void proj2_kernel(
    const ushort* __restrict__ hpack, const ushort* __restrict__ wpack,
    ushort* __restrict__ proj, int n_nodes, int nmblk)
{
    __shared__ ushort stg[4][16][136];   // per-wave 16x128 tile, +8 pad

    const int lane = threadIdx.x & 63;
    const int wv   = threadIdx.x >> 6;
    const int rr   = blockIdx.y;

    const short8* wp = reinterpret_cast<const short8*>(wpack);
    const short8* hp = reinterpret_cast<const short8*>(hpack);

    short8 X[8][4];
    #pragma unroll
    for (int fb = 0; fb < 8; ++fb)
        #pragma unroll
        for (int ks = 0; ks < 4; ++ks)
            X[fb][ks] = wp[(((rr * 8 + fb) * 4 + ks) << 6) + lane];

    const int niter = (nmblk + 3) / 4;   // block-uniform trip count

    for (int it = blockIdx.x; it < niter; it += gridDim.x) {
        const int mb = it * 4 + wv;
        const bool active = (mb < nmblk);

        f32x4 acc[8];
        #pragma unroll
        for (int fb = 0; fb < 8; ++fb) acc[fb] = f32x4{0.f, 0.f, 0.f, 0.f};

        if (active) {
            short8 Y[4];
            #pragma unroll
            for (int ks = 0; ks < 4; ++ks)
                Y[ks] = hp[((mb * 4 + ks) << 6) + lane];

            #pragma unroll
            for (int ks = 0; ks < 4; ++ks)
                #pragma unroll
                for (int fb = 0; fb < 8; ++fb)
                    acc[fb] = __builtin_amdgcn_mfma_f32_16x16x32_bf16(X[fb][ks], Y[ks], acc[fb], 0, 0, 0);
        }

        __syncthreads();   // previous iteration's reads done before rewrite

        if (active) {
            ushort (*S)[136] = stg[wv];
            #pragma unroll
            for (int fb = 0; fb < 8; ++fb) {
                uint2 d;
                d.x = (unsigned)f2bf(acc[fb][0]) | ((unsigned)f2bf(acc[fb][1]) << 16);
                d.y = (unsigned)f2bf(acc[fb][2]) | ((unsigned)f2bf(acc[fb][3]) << 16);
                *reinterpret_cast<uint2*>(&S[lane & 15][fb * 16 + (lane >> 4) * 4]) = d;
            }
        }

        __syncthreads();   // writes visible before cross-lane reads

        if (active) {
            ushort (*S)[136] = stg[wv];
            #pragma unroll
            for (int i = 0; i < 4; ++i) {
                const int row  = i * 4 + (lane >> 4);
                const int node = mb * 16 + row;
                if (node < n_nodes) {
                    uint4 v = *reinterpret_cast<const uint4*>(&S[row][(lane & 15) * 8]);
                    *reinterpret_cast<uint4*>(
                        proj + ((size_t)rr * n_nodes + node) * FEAT + (lane & 15) * 8) = v;
                }
            }
        }
    }
}

// ---------------------------------------------------------------------------
// bscan: sum NHB partials per bin, scan -> boffs[nbkt+1], gcur copy
// ---------------------------------------------------------------------------
__global__ __launch_bounds__(1024) void bscan_kernel(
    const int* __restrict__ gpart, int* __restrict__ boffs,
    int* __restrict__ gcur, int nbkt)
{
    __shared__ int part[1024];
    const int tid = threadIdx.x;
    int s = 0;
    if (tid < nbkt)
        for (int b = 0; b < NHB; ++b) s += gpart[b * 1024 + tid];
    part[tid] = s;
    __syncthreads();
    for (int d = 1; d < 1024; d <<= 1) {
        int v = (tid >= d) ? part[tid - d] : 0;
        __syncthreads();
        part[tid] += v;
        __syncthreads();
    }
    int excl = (tid > 0) ? part[tid - 1] : 0;
    if (tid < nbkt) { boffs[tid] = excl; gcur[tid] = excl; }
    if (tid == 1023) boffs[nbkt] = part[1023];
}

// ---------------------------------------------------------------------------
// Partition: LDS-staged two-pass scatter -> recs_tmp grouped by bucket.
// rec.x = src | rel<<15 | (dst&31)<<19 ; rec.y = norm bits
// ---------------------------------------------------------------------------
__global__ __launch_bounds__(256) void partition_kernel(
    const int* __restrict__ src, const int* __restrict__ dst,
    const int* __restrict__ rel, const float* __restrict__ norm,
    int* __restrict__ gcur, uint2* __restrict__ recs_tmp, int n_edges, int nbkt)
{
    __shared__ int cnt[1024];
    __shared__ int base[1024];
    __shared__ int cur[1024];
    __shared__ uint2 stage[PCHUNK];
    __shared__ ushort sbkt[PCHUNK];

    const int tid = threadIdx.x;
    const int c0 = blockIdx.x * PCHUNK;

    for (int i = tid; i < nbkt; i += 256) { cnt[i] = 0; cur[i] = 0; }
    __syncthreads();

    #pragma unroll
    for (int j = 0; j < PCHUNK / 256; ++j) {
        int slot = j * 256 + tid;
        int e = c0 + slot;
        if (e < n_edges) {
            int d = dst[e];
            int b = d >> 5;
            uint2 r;
            r.x = (unsigned)src[e] | ((unsigned)rel[e] << 15) | ((unsigned)(d & 31) << 19);
            r.y = __float_as_uint(norm[e]);
            stage[slot] = r;
            sbkt[slot] = (ushort)b;
            atomicAdd(&cnt[b], 1);
        } else {
            sbkt[slot] = 0xffffu;
        }
    }
    __syncthreads();

    for (int i = tid; i < nbkt; i += 256)
        if (cnt[i] > 0) base[i] = atomicAdd(&gcur[i], cnt[i]);
    __syncthreads();

    #pragma unroll
    for (int j = 0; j < PCHUNK / 256; ++j) {
        int slot = j * 256 + tid;
        ushort b = sbkt[slot];
        if (b != 0xffffu) {
            int rank = atomicAdd(&cur[b], 1);
            recs_tmp[base[b] + rank] = stage[slot];
        }
    }
}

// ---------------------------------------------------------------------------
// bsort: one block per bucket. Two passes over the bucket's records with
// int LDS counters/cursors -> node-sorted recs + per-node CSR offs.
// ---------------------------------------------------------------------------
__global__ __launch_bounds__(256) void bsort_kernel(
    const uint2* __restrict__ recs_tmp, const int* __restrict__ boffs,
    uint2* __restrict__ recs, int* __restrict__ offs,
    int n_nodes, int n_edges, int nbkt)
{
    __shared__ int cnt[BKT_SZ];
    __shared__ int cur[BKT_SZ];
    const int b = blockIdx.x;
    const int tid = threadIdx.x;
    const int beg = boffs[b], end = boffs[b + 1];

    if (tid < BKT_SZ) cnt[tid] = 0;
    __syncthreads();
    for (int i = beg + tid; i < end; i += 256)
        atomicAdd(&cnt[(recs_tmp[i].x >> 19) & 31u], 1);
    __syncthreads();
    if (tid == 0) {
        int run = beg;
        for (int k = 0; k < BKT_SZ; ++k) {
            int node = b * BKT_SZ + k;
            if (node < n_nodes) offs[node] = run;
            cur[k] = run;
            run += cnt[k];
        }
        if (b == nbkt - 1) offs[n_nodes] = n_edges;
    }
    __syncthreads();
    for (int i = beg + tid; i < end; i += 256) {
        uint2 r = recs_tmp[i];
        int p = atomicAdd(&cur[(r.x >> 19) & 31u], 1);
        recs[p] = r;
    }
}

// ---------------------------------------------------------------------------
// gather4: 4 nodes per wave (16 lanes x 16B = full 256B proj row per group).
// Register accumulation, 2-deep prefetch (named regs), fused ReLU, f4 stores.
// ---------------------------------------------------------------------------
__global__ __launch_bounds__(256) void gather4_kernel(
    const ushort* __restrict__ proj, const uint2* __restrict__ recs,
    const int* __restrict__ offs, float* __restrict__ out,
    int n_nodes, int n_edges)
{
    const int wid  = (int)((blockIdx.x * blockDim.x + threadIdx.x) >> 6);
    const int lane = threadIdx.x & 63;
    const int sl   = lane & 15;
    const int node = wid * 4 + (lane >> 4);
    if (node >= n_nodes) return;

    const int beg = offs[node];
    const int end = offs[node + 1];
    const int gbase = lane & 48;          // first lane of my 16-lane group

    float a0 = 0.f, a1 = 0.f, a2 = 0.f, a3 = 0.f;
    float a4 = 0.f, a5 = 0.f, a6 = 0.f, a7 = 0.f;

    for (int base = beg; base < end; base += 16) {
        int n = end - base; if (n > 16) n = 16;
        int idx = base + sl; if (idx >= end) idx = end - 1;
        uint2 r = recs[idx];

        unsigned k0 = (unsigned)__shfl((int)r.x, gbase);
        uint4 va = *reinterpret_cast<const uint4*>(proj +
            ((size_t)((k0 >> 15) & 0xfu) * n_nodes + (k0 & 0x7fffu)) * FEAT + sl * 8);
        uint4 vb = va;
        if (n > 1) {
            unsigned k1 = (unsigned)__shfl((int)r.x, gbase + 1);
            vb = *reinterpret_cast<const uint4*>(proj +
                ((size_t)((k1 >> 15) & 0xfu) * n_nodes + (k1 & 0x7fffu)) * FEAT + sl * 8);
        }

        for (int j = 0; j < n; ++j) {
            uint4 vc = va;
            va = vb;
            if (j + 2 < n) {
                unsigned k2 = (unsigned)__shfl((int)r.x, gbase + j + 2);
                vb = *reinterpret_cast<const uint4*>(proj +
                    ((size_t)((k2 >> 15) & 0xfu) * n_nodes + (k2 & 0x7fffu)) * FEAT + sl * 8);
            }
            float nmc = __uint_as_float((unsigned)__shfl((int)r.y, gbase + j));
            a0 += bf2f((ushort)(vc.x & 0xffffu)) * nmc;
            a1 += bf2f((ushort)(vc.x >> 16)) * nmc;
            a2 += bf2f((ushort)(vc.y & 0xffffu)) * nmc;
            a3 += bf2f((ushort)(vc.y >> 16)) * nmc;
            a4 += bf2f((ushort)(vc.z & 0xffffu)) * nmc;
            a5 += bf2f((ushort)(vc.z >> 16)) * nmc;
            a6 += bf2f((ushort)(vc.w & 0xffffu)) * nmc;
            a7 += bf2f((ushort)(vc.w >> 16)) * nmc;
        }
    }

    float* o = out + (size_t)node * FEAT + sl * 8;
    float4 o0, o1;
    o0.x = fmaxf(a0, 0.f); o0.y = fmaxf(a1, 0.f);
    o0.z = fmaxf(a2, 0.f); o0.w = fmaxf(a3, 0.f);
    o1.x = fmaxf(a4, 0.f); o1.y = fmaxf(a5, 0.f);
    o1.z = fmaxf(a6, 0.f); o1.w = fmaxf(a7, 0.f);
    *reinterpret_cast<float4*>(o)     = o0;
    *reinterpret_cast<float4*>(o + 4) = o1;
}

// ---------------------------------------------------------------------------
// Fallback (small ws): LDS proj + atomic edge path
// ---------------------------------------------------------------------------
constexpr int BM = 64;

__global__ __launch_bounds__(256) void proj_kernel(
    const float* __restrict__ h, const float* __restrict__ W,
    ushort* __restrict__ proj, int n_nodes, int r0)
{
    __shared__ ushort Wt[128][136];
    __shared__ ushort hs[BM][136];

    const int tid  = threadIdx.x;
    const int rel  = r0 + blockIdx.y;
    const float* Wg = W + (size_t)rel * FEAT * FEAT;

    #pragma unroll
    for (int it = 0; it < 16; ++it) {
        int f = (it * 256 + tid) * 4;
        int k = f >> 7, n = f & 127;
        float4 w4 = *reinterpret_cast<const float4*>(Wg + f);
        Wt[n + 0][k] = f2bf(w4.x);
        Wt[n + 1][k] = f2bf(w4.y);
        Wt[n + 2][k] = f2bf(w4.z);
        Wt[n + 3][k] = f2bf(w4.w);
    }

    const int lane = tid & 63;
    const int wave = tid >> 6;
    const int r    = lane & 15;
    const int kgrp = lane >> 4;

    ushort* projr = proj + (size_t)blockIdx.y * n_nodes * FEAT;
    const int nchunks = (n_nodes + BM - 1) / BM;

    for (int c = blockIdx.x; c < nchunks; c += gridDim.x) {
        const int m0 = c * BM;
        __syncthreads();
        #pragma unroll
        for (int it = 0; it < 8; ++it) {
            int f = (it * 256 + tid) * 4;
            int m = f >> 7, k = f & 127;
            int row = m0 + m;
            float4 v = make_float4(0.f, 0.f, 0.f, 0.f);
            if (row < n_nodes)
                v = *reinterpret_cast<const float4*>(h + (size_t)row * FEAT + k);
            ushort4 u;
            u.x = f2bf(v.x); u.y = f2bf(v.y); u.z = f2bf(v.z); u.w = f2bf(v.w);
            *reinterpret_cast<ushort4*>(&hs[m][k]) = u;
        }
        __syncthreads();

        f32x4 acc[8];
        #pragma unroll
        for (int i = 0; i < 8; ++i) acc[i] = f32x4{0.f, 0.f, 0.f, 0.f};

        #pragma unroll
        for (int kk = 0; kk < 4; ++kk) {
            const int kbase = kk * 32 + kgrp * 8;
            short8 a = *reinterpret_cast<const short8*>(&hs[wave * 16 + r][kbase]);
            #pragma unroll
            for (int ct = 0; ct < 8; ++ct) {
                short8 b = *reinterpret_cast<const short8*>(&Wt[ct * 16 + r][kbase]);
                acc[ct] = __builtin_amdgcn_mfma_f32_16x16x32_bf16(a, b, acc[ct], 0, 0, 0);
            }
        }

        #pragma unroll
        for (int ct = 0; ct < 8; ++ct) {
            #pragma unroll
            for (int i = 0; i < 4; ++i) {
                int row = m0 + wave * 16 + kgrp * 4 + i;
                if (row < n_nodes)
                    projr[(size_t)row * FEAT + ct * 16 + r] = f2bf(acc[ct][i]);
            }
        }
    }
}

__global__ __launch_bounds__(256) void edge_kernel(
    const ushort* __restrict__ proj, const float* __restrict__ norm,
    const int* __restrict__ src, const int* __restrict__ dst,
    const int* __restrict__ rel, float* __restrict__ out,
    int n_edges, int n_nodes, int r0, int r1)
{
    const int lane = threadIdx.x & 63;
    int gw = (int)((blockIdx.x * blockDim.x + threadIdx.x) >> 6);
    const int nw = (int)((gridDim.x * blockDim.x) >> 6);

    for (int e = gw; e < n_edges; e += nw) {
        int rr = rel[e];
        if (rr < r0 || rr >= r1) continue;
        int s = src[e];
        int d = dst[e];
        float nm = norm[e];
        const ushort* prow = proj + ((size_t)(rr - r0) * n_nodes + s) * FEAT;
        unsigned int v = *reinterpret_cast<const unsigned int*>(prow + lane * 2);
        float x0 = bf2f((ushort)(v & 0xffffu)) * nm;
        float x1 = bf2f((ushort)(v >> 16)) * nm;
        float* o = out + (size_t)d * FEAT + lane * 2;
        atomicAdd(o + 0, x0);
        atomicAdd(o + 1, x1);
    }
}

__global__ __launch_bounds__(256) void relu_kernel(float4* out, int n4)
{
    int i = blockIdx.x * blockDim.x + threadIdx.x;
    int stride = gridDim.x * blockDim.x;
    for (; i < n4; i += stride) {
        float4 v = out[i];
        v.x = fmaxf(v.x, 0.f);
        v.y = fmaxf(v.y, 0.f);
        v.z = fmaxf(v.z, 0.f);
        v.w = fmaxf(v.w, 0.f);
        out[i] = v;
    }
}

extern "C" void kernel_launch(void* const* d_in, const int* in_sizes, int n_in,
                              void* d_out, int out_size, void* d_ws, size_t ws_size,
                              hipStream_t stream)
{
    const float* h    = (const float*)d_in[0];
    const float* W    = (const float*)d_in[1];
    const float* norm = (const float*)d_in[2];
    const int*   src  = (const int*)d_in[3];
    const int*   dst  = (const int*)d_in[4];
    const int*   rel  = (const int*)d_in[5];
    float* out = (float*)d_out;

    const int n_nodes = in_sizes[0] / FEAT;   // 20000
    const int n_edges = in_sizes[3];          // 640000
    const int nmblk   = (n_nodes + 15) / 16;
    const int nbkt    = (n_nodes + BKT_SZ - 1) / BKT_SZ;   // 625

    // ws layout
    const size_t projB    = (size_t)NRELS * n_nodes * FEAT * sizeof(ushort);
    const size_t rtmpOff  = (projB + 255) & ~(size_t)255;
    const size_t recsB    = (size_t)n_edges * sizeof(uint2);
    const size_t recsOff  = (rtmpOff + recsB + 255) & ~(size_t)255;
    const size_t gpartOff = (recsOff + recsB + 255) & ~(size_t)255;
    const size_t gpartB   = (size_t)NHB * 1024 * 4;
    const size_t bktB     = ((size_t)(nbkt + 1) * 4 + 255) & ~(size_t)255;
    const size_t boffOff  = gpartOff + gpartB;
    const size_t gcurOff  = boffOff + bktB;
    const size_t offsOff  = gcurOff + bktB;
    const size_t offsB    = ((size_t)(n_nodes + 1) * 4 + 255) & ~(size_t)255;
    const size_t hpackOff = offsOff + offsB;
    const size_t hpackB   = ((size_t)nmblk * 256 * 8 * sizeof(ushort) + 255) & ~(size_t)255;
    const size_t wpackOff = hpackOff + hpackB;
    const size_t wpackB   = (size_t)NRELS * 8 * 4 * 64 * 8 * sizeof(ushort);
    const size_t need     = wpackOff + wpackB;

    if (ws_size >= need && n_nodes < 32768 && nbkt <= 1024) {
        ushort* proj   = (ushort*)d_ws;
        uint2*  rtmp   = (uint2*)((char*)d_ws + rtmpOff);
        uint2*  recs   = (uint2*)((char*)d_ws + recsOff);
        int*    gpart  = (int*)((char*)d_ws + gpartOff);
        int*    boffs  = (int*)((char*)d_ws + boffOff);
        int*    gcur   = (int*)((char*)d_ws + gcurOff);
        int*    offs   = (int*)((char*)d_ws + offsOff);
        ushort* hpack  = (ushort*)((char*)d_ws + hpackOff);
        ushort* wpack  = (ushort*)((char*)d_ws + wpackOff);

        prep_kernel<<<nmblk + 128 + NHB, 256, 0, stream>>>(
            h, W, dst, hpack, wpack, gpart, n_nodes, nmblk, n_edges, nbkt);

        dim3 g1(128, NRELS);
        proj2_kernel<<<g1, 256, 0, stream>>>(hpack, wpack, proj, n_nodes, nmblk);

        bscan_kernel<<<1, 1024, 0, stream>>>(gpart, boffs, gcur, nbkt);
        partition_kernel<<<(n_edges + PCHUNK - 1) / PCHUNK, 256, 0, stream>>>(
            src, dst, rel, norm, gcur, rtmp, n_edges, nbkt);
        bsort_kernel<<<nbkt, 256, 0, stream>>>(rtmp, boffs, recs, offs,
                                               n_nodes, n_edges, nbkt);

        const int nwaves = (n_nodes + 3) / 4;
        gather4_kernel<<<(nwaves * 64 + 255) / 256, 256, 0, stream>>>(
            proj, recs, offs, out, n_nodes, n_edges);
    } else {
        // fallback: relation-chunked atomic path
        ushort* proj = (ushort*)d_ws;
        hipMemsetAsync(out, 0, (size_t)out_size * sizeof(float), stream);
        const size_t perRel = (size_t)n_nodes * FEAT * sizeof(ushort);
        int rc = (int)(ws_size / perRel);
        if (rc < 1) rc = 1;
        if (rc > NRELS) rc = NRELS;
        for (int r0 = 0; r0 < NRELS; r0 += rc) {
            const int rcc = (rc < NRELS - r0) ? rc : (NRELS - r0);
            dim3 g1(32, rcc);
            proj_kernel<<<g1, 256, 0, stream>>>(h, W, proj, n_nodes, r0);
            edge_kernel<<<1024, 256, 0, stream>>>(proj, norm, src, dst, rel, out,
                                                  n_edges, n_nodes, r0, r0 + rcc);
        }
        relu_kernel<<<2048, 256, 0, stream>>>((float4*)out, out_size / 4);
    }
}

// Round 9
// 93.080 us; speedup vs baseline: 6.4263x; 1.1268x over previous
//
#include <hip/hip_runtime.h>
#include <hip/hip_bf16.h>

#define FEAT 128
#define NRELS 16
#define BKT_SZ 32          // dst nodes per bucket
#define PCHUNK 4096        // edges per partition block (16 per thread)
#define NHB 256            // histogram partial blocks

using short8 = __attribute__((ext_vector_type(8))) short;
using f32x4  = __attribute__((ext_vector_type(4))) float;

__device__ inline ushort f2bf(float x) {
    union { float f; unsigned int u; } v; v.f = x;
    unsigned int u = v.u;
    unsigned int r = (u + 0x7fffu + ((u >> 16) & 1u)) >> 16;  // RNE
    return (ushort)r;
}
__device__ inline float bf2f(ushort b) {
    union { unsigned int u; float f; } v; v.u = ((unsigned int)b) << 16;
    return v.f;
}

// ---------------------------------------------------------------------------
// prep: fused pack_h + pack_w + bucket-histogram-partials (role by blockIdx).
// ---------------------------------------------------------------------------
__global__ __launch_bounds__(256) void prep_kernel(
    const float* __restrict__ h, const float* __restrict__ W,
    const int* __restrict__ dst,
    ushort* __restrict__ hpack, ushort* __restrict__ wpack,
    int* __restrict__ gpart,
    int n_nodes, int nmblk, int n_edges, int nbkt)
{
    const int bid = blockIdx.x;
    if (bid < nmblk) {
        // ---- pack_h ----
        int t = bid * 256 + threadIdx.x;
        int lane = t & 63;
        int mblk = t >> 8;
        int ks   = (t >> 6) & 3;
        int row  = mblk * 16 + (lane & 15);
        int k0   = ks * 32 + (lane >> 4) * 8;

        ushort u[8] = {0, 0, 0, 0, 0, 0, 0, 0};
        if (row < n_nodes) {
            const float* p = h + (size_t)row * FEAT + k0;
            float4 a = *reinterpret_cast<const float4*>(p);
            float4 b = *reinterpret_cast<const float4*>(p + 4);
            u[0] = f2bf(a.x); u[1] = f2bf(a.y); u[2] = f2bf(a.z); u[3] = f2bf(a.w);
            u[4] = f2bf(b.x); u[5] = f2bf(b.y); u[6] = f2bf(b.z); u[7] = f2bf(b.w);
        }
        *reinterpret_cast<short8*>(hpack + (size_t)t * 8) = *reinterpret_cast<short8*>(u);
    } else if (bid < nmblk + 128) {
        // ---- pack_w (128 blocks cover NRELS*8*4*64 = 32768 threads) ----
        int t = (bid - nmblk) * 256 + threadIdx.x;
        int lane = t & 63;
        int ks   = (t >> 6) & 3;
        int fb   = (t >> 8) & 7;
        int r    = t >> 11;
        int k0   = ks * 32 + (lane >> 4) * 8;
        int f    = fb * 16 + (lane & 15);

        ushort u[8];
        #pragma unroll
        for (int j = 0; j < 8; ++j)
            u[j] = f2bf(W[((size_t)r * FEAT + (k0 + j)) * FEAT + f]);
        *reinterpret_cast<short8*>(wpack + (size_t)t * 8) = *reinterpret_cast<short8*>(u);
    } else {
        // ---- bucket histogram partials (non-atomic global, LDS-staged) ----
        const int hb = bid - nmblk - 128;     // 0..NHB-1
        __shared__ int cnt[1024];
        for (int i = threadIdx.x; i < 1024; i += 256) cnt[i] = 0;
        __syncthreads();
        for (int i = hb * 256 + threadIdx.x; i < n_edges; i += NHB * 256)
            atomicAdd(&cnt[dst[i] >> 5], 1);
        __syncthreads();
        for (int i = threadIdx.x; i < nbkt; i += 256)
            gpart[hb * 1024 + i] = cnt[i];
    }
}

// ---------------------------------------------------------------------------
// bscan: sum NHB partials per bin, scan -> boffs[nbkt+1], gcur copy
// ---------------------------------------------------------------------------
__global__ __launch_bounds__(1024) void bscan_kernel(
    const int* __restrict__ gpart, int* __restrict__ boffs,
    int* __restrict__ gcur, int nbkt)
{
    __shared__ int part[1024];
    const int tid = threadIdx.x;
    int s = 0;
    if (tid < nbkt)
        for (int b = 0; b < NHB; ++b) s += gpart[b * 1024 + tid];
    part[tid] = s;
    __syncthreads();
    for (int d = 1; d < 1024; d <<= 1) {
        int v = (tid >= d) ? part[tid - d] : 0;
        __syncthreads();
        part[tid] += v;
        __syncthreads();
    }
    int excl = (tid > 0) ? part[tid - 1] : 0;
    if (tid < nbkt) { boffs[tid] = excl; gcur[tid] = excl; }
    if (tid == 1023) boffs[nbkt] = part[1023];
}

// ---------------------------------------------------------------------------
// fused2: partition-role blocks [0, nchunks) run FIRST (start immediately,
// hide under proj), proj-role blocks [nchunks, nchunks+2048) do the MFMA
// projection. 52KB smem char array unioned per role.
//
// partition: LDS-staged two-pass scatter -> recs_tmp grouped by bucket.
//   rec.x = src | rel<<15 | (dst&31)<<19 ; rec.y = norm bits
// proj: proj[r][n][f] = h[n][:] @ W[r][:][f]; D = mfma(Wfrag,hfrag):
//   node = lane&15, feat = fb*16+(lane>>4)*4+i; LDS-staged coalesced stores.
// ---------------------------------------------------------------------------
__global__ __launch_bounds__(256) void fused2_kernel(
    const ushort* __restrict__ hpack, const ushort* __restrict__ wpack,
    ushort* __restrict__ proj,
    const int* __restrict__ src, const int* __restrict__ dst,
    const int* __restrict__ rel, const float* __restrict__ norm,
    int* __restrict__ gcur, uint2* __restrict__ recs_tmp,
    int n_nodes, int nmblk, int n_edges, int nbkt, int nchunks)
{
    __shared__ __align__(16) char smem[53248];

    if ((int)blockIdx.x < nchunks) {
        // ---------------- partition role ----------------
        int*    cnt   = (int*)smem;          // 1024
        int*    base  = cnt + 1024;          // 1024
        int*    cur   = base + 1024;         // 1024
        uint2*  stage = (uint2*)(cur + 1024);       // PCHUNK
        ushort* sbkt  = (ushort*)(stage + PCHUNK);  // PCHUNK

        const int tid = threadIdx.x;
        const int c0 = blockIdx.x * PCHUNK;

        for (int i = tid; i < nbkt; i += 256) { cnt[i] = 0; cur[i] = 0; }
        __syncthreads();

        #pragma unroll
        for (int j = 0; j < PCHUNK / 256; ++j) {
            int slot = j * 256 + tid;
            int e = c0 + slot;
            if (e < n_edges) {
                int d = dst[e];
                int b = d >> 5;
                uint2 r;
                r.x = (unsigned)src[e] | ((unsigned)rel[e] << 15) | ((unsigned)(d & 31) << 19);
                r.y = __float_as_uint(norm[e]);
                stage[slot] = r;
                sbkt[slot] = (ushort)b;
                atomicAdd(&cnt[b], 1);
            } else {
                sbkt[slot] = 0xffffu;
            }
        }
        __syncthreads();

        for (int i = tid; i < nbkt; i += 256)
            if (cnt[i] > 0) base[i] = atomicAdd(&gcur[i], cnt[i]);
        __syncthreads();

        #pragma unroll
        for (int j = 0; j < PCHUNK / 256; ++j) {
            int slot = j * 256 + tid;
            ushort b = sbkt[slot];
            if (b != 0xffffu) {
                int rank = atomicAdd(&cur[b], 1);
                recs_tmp[base[b] + rank] = stage[slot];
            }
        }
    } else {
        // ---------------- proj role ----------------
        const int bid2 = (int)blockIdx.x - nchunks;
        const int rr   = bid2 >> 7;          // 0..NRELS-1
        const int bx   = bid2 & 127;

        const int lane = threadIdx.x & 63;
        const int wv   = threadIdx.x >> 6;
        ushort (*S)[136] = reinterpret_cast<ushort(*)[136]>(smem + wv * (16 * 136 * 2));

        const short8* wp = reinterpret_cast<const short8*>(wpack);
        const short8* hp = reinterpret_cast<const short8*>(hpack);

        short8 X[8][4];
        #pragma unroll
        for (int fb = 0; fb < 8; ++fb)
            #pragma unroll
            for (int ks = 0; ks < 4; ++ks)
                X[fb][ks] = wp[(((rr * 8 + fb) * 4 + ks) << 6) + lane];

        const int niter = (nmblk + 3) / 4;   // block-uniform trip count

        for (int it = bx; it < niter; it += 128) {
            const int mb = it * 4 + wv;
            const bool active = (mb < nmblk);

            f32x4 acc[8];
            #pragma unroll
            for (int fb = 0; fb < 8; ++fb) acc[fb] = f32x4{0.f, 0.f, 0.f, 0.f};

            if (active) {
                short8 Y[4];
                #pragma unroll
                for (int ks = 0; ks < 4; ++ks)
                    Y[ks] = hp[((mb * 4 + ks) << 6) + lane];

                #pragma unroll
                for (int ks = 0; ks < 4; ++ks)
                    #pragma unroll
                    for (int fb = 0; fb < 8; ++fb)
                        acc[fb] = __builtin_amdgcn_mfma_f32_16x16x32_bf16(X[fb][ks], Y[ks], acc[fb], 0, 0, 0);
            }

            __syncthreads();   // previous iteration's reads done before rewrite

            if (active) {
                #pragma unroll
                for (int fb = 0; fb < 8; ++fb) {
                    uint2 d;
                    d.x = (unsigned)f2bf(acc[fb][0]) | ((unsigned)f2bf(acc[fb][1]) << 16);
                    d.y = (unsigned)f2bf(acc[fb][2]) | ((unsigned)f2bf(acc[fb][3]) << 16);
                    *reinterpret_cast<uint2*>(&S[lane & 15][fb * 16 + (lane >> 4) * 4]) = d;
                }
            }

            __syncthreads();   // writes visible before cross-lane reads

            if (active) {
                #pragma unroll
                for (int i = 0; i < 4; ++i) {
                    const int row  = i * 4 + (lane >> 4);
                    const int node = mb * 16 + row;
                    if (node < n_nodes) {
                        uint4 v = *reinterpret_cast<const uint4*>(&S[row][(lane & 15) * 8]);
                        *reinterpret_cast<uint4*>(
                            proj + ((size_t)rr * n_nodes + node) * FEAT + (lane & 15) * 8) = v;
                    }
                }
            }
        }
    }
}

// ---------------------------------------------------------------------------
// bsort: one block per bucket. Two passes over the bucket's records with
// int LDS counters/cursors -> node-sorted recs + per-node CSR offs.
// ---------------------------------------------------------------------------
__global__ __launch_bounds__(256) void bsort_kernel(
    const uint2* __restrict__ recs_tmp, const int* __restrict__ boffs,
    uint2* __restrict__ recs, int* __restrict__ offs,
    int n_nodes, int n_edges, int nbkt)
{
    __shared__ int cnt[BKT_SZ];
    __shared__ int cur[BKT_SZ];
    const int b = blockIdx.x;
    const int tid = threadIdx.x;
    const int beg = boffs[b], end = boffs[b + 1];

    if (tid < BKT_SZ) cnt[tid] = 0;
    __syncthreads();
    for (int i = beg + tid; i < end; i += 256)
        atomicAdd(&cnt[(recs_tmp[i].x >> 19) & 31u], 1);
    __syncthreads();
    if (tid == 0) {
        int run = beg;
        for (int k = 0; k < BKT_SZ; ++k) {
            int node = b * BKT_SZ + k;
            if (node < n_nodes) offs[node] = run;
            cur[k] = run;
            run += cnt[k];
        }
        if (b == nbkt - 1) offs[n_nodes] = n_edges;
    }
    __syncthreads();
    for (int i = beg + tid; i < end; i += 256) {
        uint2 r = recs_tmp[i];
        int p = atomicAdd(&cur[(r.x >> 19) & 31u], 1);
        recs[p] = r;
    }
}

// ---------------------------------------------------------------------------
// gather4: 4 nodes per wave (16 lanes x 16B = full 256B proj row per group).
// Register accumulation, 3-deep prefetch (named regs), fused ReLU, f4 stores.
// ---------------------------------------------------------------------------
__global__ __launch_bounds__(256) void gather4_kernel(
    const ushort* __restrict__ proj, const uint2* __restrict__ recs,
    const int* __restrict__ offs, float* __restrict__ out,
    int n_nodes, int n_edges)
{
    const int wid  = (int)((blockIdx.x * blockDim.x + threadIdx.x) >> 6);
    const int lane = threadIdx.x & 63;
    const int sl   = lane & 15;
    const int node = wid * 4 + (lane >> 4);
    if (node >= n_nodes) return;

    const int beg = offs[node];
    const int end = offs[node + 1];
    const int gbase = lane & 48;          // first lane of my 16-lane group

    float a0 = 0.f, a1 = 0.f, a2 = 0.f, a3 = 0.f;
    float a4 = 0.f, a5 = 0.f, a6 = 0.f, a7 = 0.f;

    for (int base = beg; base < end; base += 16) {
        int n = end - base; if (n > 16) n = 16;
        int idx = base + sl; if (idx >= end) idx = end - 1;
        uint2 r = recs[idx];

        unsigned k0 = (unsigned)__shfl((int)r.x, gbase);
        uint4 va = *reinterpret_cast<const uint4*>(proj +
            ((size_t)((k0 >> 15) & 0xfu) * n_nodes + (k0 & 0x7fffu)) * FEAT + sl * 8);
        uint4 vb = va, vc2 = va;
        if (n > 1) {
            unsigned k1 = (unsigned)__shfl((int)r.x, gbase + 1);
            vb = *reinterpret_cast<const uint4*>(proj +
                ((size_t)((k1 >> 15) & 0xfu) * n_nodes + (k1 & 0x7fffu)) * FEAT + sl * 8);
        }
        if (n > 2) {
            unsigned k2 = (unsigned)__shfl((int)r.x, gbase + 2);
            vc2 = *reinterpret_cast<const uint4*>(proj +
                ((size_t)((k2 >> 15) & 0xfu) * n_nodes + (k2 & 0x7fffu)) * FEAT + sl * 8);
        }

        for (int j = 0; j < n; ++j) {
            uint4 vcur = va;
            va = vb;
            vb = vc2;
            if (j + 3 < n) {
                unsigned k3 = (unsigned)__shfl((int)r.x, gbase + j + 3);
                vc2 = *reinterpret_cast<const uint4*>(proj +
                    ((size_t)((k3 >> 15) & 0xfu) * n_nodes + (k3 & 0x7fffu)) * FEAT + sl * 8);
            }
            float nmc = __uint_as_float((unsigned)__shfl((int)r.y, gbase + j));
            a0 += bf2f((ushort)(vcur.x & 0xffffu)) * nmc;
            a1 += bf2f((ushort)(vcur.x >> 16)) * nmc;
            a2 += bf2f((ushort)(vcur.y & 0xffffu)) * nmc;
            a3 += bf2f((ushort)(vcur.y >> 16)) * nmc;
            a4 += bf2f((ushort)(vcur.z & 0xffffu)) * nmc;
            a5 += bf2f((ushort)(vcur.z >> 16)) * nmc;
            a6 += bf2f((ushort)(vcur.w & 0xffffu)) * nmc;
            a7 += bf2f((ushort)(vcur.w >> 16)) * nmc;
        }
    }

    float* o = out + (size_t)node * FEAT + sl * 8;
    float4 o0, o1;
    o0.x = fmaxf(a0, 0.f); o0.y = fmaxf(a1, 0.f);
    o0.z = fmaxf(a2, 0.f); o0.w = fmaxf(a3, 0.f);
    o1.x = fmaxf(a4, 0.f); o1.y = fmaxf(a5, 0.f);
    o1.z = fmaxf(a6, 0.f); o1.w = fmaxf(a7, 0.f);
    *reinterpret_cast<float4*>(o)     = o0;
    *reinterpret_cast<float4*>(o + 4) = o1;
}

// ---------------------------------------------------------------------------
// Fallback (small ws): LDS proj + atomic edge path
// ---------------------------------------------------------------------------
constexpr int BM = 64;

__global__ __launch_bounds__(256) void proj_kernel(
    const float* __restrict__ h, const float* __restrict__ W,
    ushort* __restrict__ proj, int n_nodes, int r0)
{
    __shared__ ushort Wt[128][136];
    __shared__ ushort hs[BM][136];

    const int tid  = threadIdx.x;
    const int rel  = r0 + blockIdx.y;
    const float* Wg = W + (size_t)rel * FEAT * FEAT;

    #pragma unroll
    for (int it = 0; it < 16; ++it) {
        int f = (it * 256 + tid) * 4;
        int k = f >> 7, n = f & 127;
        float4 w4 = *reinterpret_cast<const float4*>(Wg + f);
        Wt[n + 0][k] = f2bf(w4.x);
        Wt[n + 1][k] = f2bf(w4.y);
        Wt[n + 2][k] = f2bf(w4.z);
        Wt[n + 3][k] = f2bf(w4.w);
    }

    const int lane = tid & 63;
    const int wave = tid >> 6;
    const int r    = lane & 15;
    const int kgrp = lane >> 4;

    ushort* projr = proj + (size_t)blockIdx.y * n_nodes * FEAT;
    const int nchunks = (n_nodes + BM - 1) / BM;

    for (int c = blockIdx.x; c < nchunks; c += gridDim.x) {
        const int m0 = c * BM;
        __syncthreads();
        #pragma unroll
        for (int it = 0; it < 8; ++it) {
            int f = (it * 256 + tid) * 4;
            int m = f >> 7, k = f & 127;
            int row = m0 + m;
            float4 v = make_float4(0.f, 0.f, 0.f, 0.f);
            if (row < n_nodes)
                v = *reinterpret_cast<const float4*>(h + (size_t)row * FEAT + k);
            ushort4 u;
            u.x = f2bf(v.x); u.y = f2bf(v.y); u.z = f2bf(v.z); u.w = f2bf(v.w);
            *reinterpret_cast<ushort4*>(&hs[m][k]) = u;
        }
        __syncthreads();

        f32x4 acc[8];
        #pragma unroll
        for (int i = 0; i < 8; ++i) acc[i] = f32x4{0.f, 0.f, 0.f, 0.f};

        #pragma unroll
        for (int kk = 0; kk < 4; ++kk) {
            const int kbase = kk * 32 + kgrp * 8;
            short8 a = *reinterpret_cast<const short8*>(&hs[wave * 16 + r][kbase]);
            #pragma unroll
            for (int ct = 0; ct < 8; ++ct) {
                short8 b = *reinterpret_cast<const short8*>(&Wt[ct * 16 + r][kbase]);
                acc[ct] = __builtin_amdgcn_mfma_f32_16x16x32_bf16(a, b, acc[ct], 0, 0, 0);
            }
        }

        #pragma unroll
        for (int ct = 0; ct < 8; ++ct) {
            #pragma unroll
            for (int i = 0; i < 4; ++i) {
                int row = m0 + wave * 16 + kgrp * 4 + i;
                if (row < n_nodes)
                    projr[(size_t)row * FEAT + ct * 16 + r] = f2bf(acc[ct][i]);
            }
        }
    }
}

__global__ __launch_bounds__(256) void edge_kernel(
    const ushort* __restrict__ proj, const float* __restrict__ norm,
    const int* __restrict__ src, const int* __restrict__ dst,
    const int* __restrict__ rel, float* __restrict__ out,
    int n_edges, int n_nodes, int r0, int r1)
{
    const int lane = threadIdx.x & 63;
    int gw = (int)((blockIdx.x * blockDim.x + threadIdx.x) >> 6);
    const int nw = (int)((gridDim.x * blockDim.x) >> 6);

    for (int e = gw; e < n_edges; e += nw) {
        int rr = rel[e];
        if (rr < r0 || rr >= r1) continue;
        int s = src[e];
        int d = dst[e];
        float nm = norm[e];
        const ushort* prow = proj + ((size_t)(rr - r0) * n_nodes + s) * FEAT;
        unsigned int v = *reinterpret_cast<const unsigned int*>(prow + lane * 2);
        float x0 = bf2f((ushort)(v & 0xffffu)) * nm;
        float x1 = bf2f((ushort)(v >> 16)) * nm;
        float* o = out + (size_t)d * FEAT + lane * 2;
        atomicAdd(o + 0, x0);
        atomicAdd(o + 1, x1);
    }
}

__global__ __launch_bounds__(256) void relu_kernel(float4* out, int n4)
{
    int i = blockIdx.x * blockDim.x + threadIdx.x;
    int stride = gridDim.x * blockDim.x;
    for (; i < n4; i += stride) {
        float4 v = out[i];
        v.x = fmaxf(v.x, 0.f);
        v.y = fmaxf(v.y, 0.f);
        v.z = fmaxf(v.z, 0.f);
        v.w = fmaxf(v.w, 0.f);
        out[i] = v;
    }
}

extern "C" void kernel_launch(void* const* d_in, const int* in_sizes, int n_in,
                              void* d_out, int out_size, void* d_ws, size_t ws_size,
                              hipStream_t stream)
{
    const float* h    = (const float*)d_in[0];
    const float* W    = (const float*)d_in[1];
    const float* norm = (const float*)d_in[2];
    const int*   src  = (const int*)d_in[3];
    const int*   dst  = (const int*)d_in[4];
    const int*   rel  = (const int*)d_in[5];
    float* out = (float*)d_out;

    const int n_nodes = in_sizes[0] / FEAT;   // 20000
    const int n_edges = in_sizes[3];          // 640000
    const int nmblk   = (n_nodes + 15) / 16;
    const int nbkt    = (n_nodes + BKT_SZ - 1) / BKT_SZ;   // 625
    const int nchunks = (n_edges + PCHUNK - 1) / PCHUNK;   // 157

    // ws layout
    const size_t projB    = (size_t)NRELS * n_nodes * FEAT * sizeof(ushort);
    const size_t rtmpOff  = (projB + 255) & ~(size_t)255;
    const size_t recsB    = (size_t)n_edges * sizeof(uint2);
    const size_t recsOff  = (rtmpOff + recsB + 255) & ~(size_t)255;
    const size_t gpartOff = (recsOff + recsB + 255) & ~(size_t)255;
    const size_t gpartB   = (size_t)NHB * 1024 * 4;
    const size_t bktB     = ((size_t)(nbkt + 1) * 4 + 255) & ~(size_t)255;
    const size_t boffOff  = gpartOff + gpartB;
    const size_t gcurOff  = boffOff + bktB;
    const size_t offsOff  = gcurOff + bktB;
    const size_t offsB    = ((size_t)(n_nodes + 1) * 4 + 255) & ~(size_t)255;
    const size_t hpackOff = offsOff + offsB;
    const size_t hpackB   = ((size_t)nmblk * 256 * 8 * sizeof(ushort) + 255) & ~(size_t)255;
    const size_t wpackOff = hpackOff + hpackB;
    const size_t wpackB   = (size_t)NRELS * 8 * 4 * 64 * 8 * sizeof(ushort);
    const size_t need     = wpackOff + wpackB;

    if (ws_size >= need && n_nodes < 32768 && nbkt <= 1024) {
        ushort* proj   = (ushort*)d_ws;
        uint2*  rtmp   = (uint2*)((char*)d_ws + rtmpOff);
        uint2*  recs   = (uint2*)((char*)d_ws + recsOff);
        int*    gpart  = (int*)((char*)d_ws + gpartOff);
        int*    boffs  = (int*)((char*)d_ws + boffOff);
        int*    gcur   = (int*)((char*)d_ws + gcurOff);
        int*    offs   = (int*)((char*)d_ws + offsOff);
        ushort* hpack  = (ushort*)((char*)d_ws + hpackOff);
        ushort* wpack  = (ushort*)((char*)d_ws + wpackOff);

        prep_kernel<<<nmblk + 128 + NHB, 256, 0, stream>>>(
            h, W, dst, hpack, wpack, gpart, n_nodes, nmblk, n_edges, nbkt);

        bscan_kernel<<<1, 1024, 0, stream>>>(gpart, boffs, gcur, nbkt);

        fused2_kernel<<<nchunks + NRELS * 128, 256, 0, stream>>>(
            hpack, wpack, proj, src, dst, rel, norm, gcur, rtmp,
            n_nodes, nmblk, n_edges, nbkt, nchunks);

        bsort_kernel<<<nbkt, 256, 0, stream>>>(rtmp, boffs, recs, offs,
                                               n_nodes, n_edges, nbkt);

        const int nwaves = (n_nodes + 3) / 4;
        gather4_kernel<<<(nwaves * 64 + 255) / 256, 256, 0, stream>>>(
            proj, recs, offs, out, n_nodes, n_edges);
    } else {
        // fallback: relation-chunked atomic path
        ushort* proj = (ushort*)d_ws;
        hipMemsetAsync(out, 0, (size_t)out_size * sizeof(float), stream);
        const size_t perRel = (size_t)n_nodes * FEAT * sizeof(ushort);
        int rc = (int)(ws_size / perRel);
        if (rc < 1) rc = 1;
        if (rc > NRELS) rc = NRELS;
        for (int r0 = 0; r0 < NRELS; r0 += rc) {
            const int rcc = (rc < NRELS - r0) ? rc : (NRELS - r0);
            dim3 g1(32, rcc);
            proj_kernel<<<g1, 256, 0, stream>>>(h, W, proj, n_nodes, r0);
            edge_kernel<<<1024, 256, 0, stream>>>(proj, norm, src, dst, rel, out,
                                                  n_edges, n_nodes, r0, r0 + rcc);
        }
        relu_kernel<<<2048, 256, 0, stream>>>((float4*)out, out_size / 4);
    }
}

// Round 10
// 74.159 us; speedup vs baseline: 8.0659x; 1.2551x over previous
//
#include <hip/hip_runtime.h>
#include <hip/hip_bf16.h>

#define FEAT 128
#define NRELS 16
#define BKT_SZ 32          // dst nodes per bucket
#define PCHUNK 4096        // edges per partition block (16 per thread)
#define CAP 2048           // fixed record capacity per bucket slab

using short8 = __attribute__((ext_vector_type(8))) short;
using f32x4  = __attribute__((ext_vector_type(4))) float;

__device__ inline ushort f2bf(float x) {
    union { float f; unsigned int u; } v; v.f = x;
    unsigned int u = v.u;
    unsigned int r = (u + 0x7fffu + ((u >> 16) & 1u)) >> 16;  // RNE
    return (ushort)r;
}
__device__ inline float bf2f(ushort b) {
    union { unsigned int u; float f; } v; v.u = ((unsigned int)b) << 16;
    return v.f;
}

// ---------------------------------------------------------------------------
// prep: fused pack_h + pack_w + zero(gcur,ovf_cnt)  (role by blockIdx).
// ---------------------------------------------------------------------------
__global__ __launch_bounds__(256) void prep_kernel(
    const float* __restrict__ h, const float* __restrict__ W,
    ushort* __restrict__ hpack, ushort* __restrict__ wpack,
    int* __restrict__ gcur,                       // gcur[nbkt] + ovf_cnt at [nbkt]
    int n_nodes, int nmblk, int nbkt)
{
    const int bid = blockIdx.x;
    if (bid < nmblk) {
        // ---- pack_h: hpack[(mblk*4+ks)*64+lane][j] ----
        int t = bid * 256 + threadIdx.x;
        int lane = t & 63;
        int mblk = t >> 8;
        int ks   = (t >> 6) & 3;
        int row  = mblk * 16 + (lane & 15);
        int k0   = ks * 32 + (lane >> 4) * 8;

        ushort u[8] = {0, 0, 0, 0, 0, 0, 0, 0};
        if (row < n_nodes) {
            const float* p = h + (size_t)row * FEAT + k0;
            float4 a = *reinterpret_cast<const float4*>(p);
            float4 b = *reinterpret_cast<const float4*>(p + 4);
            u[0] = f2bf(a.x); u[1] = f2bf(a.y); u[2] = f2bf(a.z); u[3] = f2bf(a.w);
            u[4] = f2bf(b.x); u[5] = f2bf(b.y); u[6] = f2bf(b.z); u[7] = f2bf(b.w);
        }
        *reinterpret_cast<short8*>(hpack + (size_t)t * 8) = *reinterpret_cast<short8*>(u);
    } else if (bid < nmblk + 128) {
        // ---- pack_w ----
        int t = (bid - nmblk) * 256 + threadIdx.x;
        int lane = t & 63;
        int ks   = (t >> 6) & 3;
        int fb   = (t >> 8) & 7;
        int r    = t >> 11;
        int k0   = ks * 32 + (lane >> 4) * 8;
        int f    = fb * 16 + (lane & 15);

        ushort u[8];
        #pragma unroll
        for (int j = 0; j < 8; ++j)
            u[j] = f2bf(W[((size_t)r * FEAT + (k0 + j)) * FEAT + f]);
        *reinterpret_cast<short8*>(wpack + (size_t)t * 8) = *reinterpret_cast<short8*>(u);
    } else {
        // ---- zero gcur + ovf counter ----
        for (int i = threadIdx.x; i < nbkt + 1; i += 256) gcur[i] = 0;
    }
}

// ---------------------------------------------------------------------------
// fused2: partition-role blocks [0, nchunks) + proj-role blocks (MFMA).
// partition: two-pass LDS-staged scatter into fixed bucket slabs
//   rtmp[b*CAP + pos]; pos>=CAP -> edge index to ovf list (practically never).
//   rec.x = src | rel<<15 | (dst&31)<<19 ; rec.y = norm bits
// proj: proj[r][n][f] = h[n][:] @ W[r][:][f]; D = mfma(Wfrag,hfrag):
//   node = lane&15, feat = fb*16+(lane>>4)*4+i; LDS-staged coalesced stores.
// ---------------------------------------------------------------------------
__global__ __launch_bounds__(256) void fused2_kernel(
    const ushort* __restrict__ hpack, const ushort* __restrict__ wpack,
    ushort* __restrict__ proj,
    const int* __restrict__ src, const int* __restrict__ dst,
    const int* __restrict__ rel, const float* __restrict__ norm,
    int* __restrict__ gcur, uint2* __restrict__ rtmp, int* __restrict__ ovf,
    int n_nodes, int nmblk, int n_edges, int nbkt, int nchunks)
{
    __shared__ __align__(16) char smem[53248];

    if ((int)blockIdx.x < nchunks) {
        // ---------------- partition role ----------------
        int*    cnt   = (int*)smem;                 // 1024
        int*    base  = cnt + 1024;                 // 1024
        int*    cur   = base + 1024;                // 1024
        uint2*  stage = (uint2*)(cur + 1024);       // PCHUNK
        ushort* sbkt  = (ushort*)(stage + PCHUNK);  // PCHUNK

        const int tid = threadIdx.x;
        const int c0 = blockIdx.x * PCHUNK;
        int* ovf_cnt = gcur + nbkt;

        for (int i = tid; i < nbkt; i += 256) { cnt[i] = 0; cur[i] = 0; }
        __syncthreads();

        #pragma unroll
        for (int j = 0; j < PCHUNK / 256; ++j) {
            int slot = j * 256 + tid;
            int e = c0 + slot;
            if (e < n_edges) {
                int d = dst[e];
                int b = d >> 5;
                uint2 r;
                r.x = (unsigned)src[e] | ((unsigned)rel[e] << 15) | ((unsigned)(d & 31) << 19);
                r.y = __float_as_uint(norm[e]);
                stage[slot] = r;
                sbkt[slot] = (ushort)b;
                atomicAdd(&cnt[b], 1);
            } else {
                sbkt[slot] = 0xffffu;
            }
        }
        __syncthreads();

        for (int i = tid; i < nbkt; i += 256)
            if (cnt[i] > 0) base[i] = atomicAdd(&gcur[i], cnt[i]);
        __syncthreads();

        #pragma unroll
        for (int j = 0; j < PCHUNK / 256; ++j) {
            int slot = j * 256 + tid;
            ushort b = sbkt[slot];
            if (b != 0xffffu) {
                int rank = atomicAdd(&cur[b], 1);
                int pos = base[b] + rank;
                if (pos < CAP)
                    rtmp[(size_t)b * CAP + pos] = stage[slot];
                else
                    ovf[atomicAdd(ovf_cnt, 1)] = c0 + slot;   // raw edge index
            }
        }
    } else {
        // ---------------- proj role ----------------
        const int bid2 = (int)blockIdx.x - nchunks;
        const int rr   = bid2 >> 7;          // 0..NRELS-1
        const int bx   = bid2 & 127;

        const int lane = threadIdx.x & 63;
        const int wv   = threadIdx.x >> 6;
        ushort (*S)[136] = reinterpret_cast<ushort(*)[136]>(smem + wv * (16 * 136 * 2));

        const short8* wp = reinterpret_cast<const short8*>(wpack);
        const short8* hp = reinterpret_cast<const short8*>(hpack);

        short8 X[8][4];
        #pragma unroll
        for (int fb = 0; fb < 8; ++fb)
            #pragma unroll
            for (int ks = 0; ks < 4; ++ks)
                X[fb][ks] = wp[(((rr * 8 + fb) * 4 + ks) << 6) + lane];

        const int niter = (nmblk + 3) / 4;   // block-uniform trip count

        for (int it = bx; it < niter; it += 128) {
            const int mb = it * 4 + wv;
            const bool active = (mb < nmblk);

            f32x4 acc[8];
            #pragma unroll
            for (int fb = 0; fb < 8; ++fb) acc[fb] = f32x4{0.f, 0.f, 0.f, 0.f};

            if (active) {
                short8 Y[4];
                #pragma unroll
                for (int ks = 0; ks < 4; ++ks)
                    Y[ks] = hp[((mb * 4 + ks) << 6) + lane];

                #pragma unroll
                for (int ks = 0; ks < 4; ++ks)
                    #pragma unroll
                    for (int fb = 0; fb < 8; ++fb)
                        acc[fb] = __builtin_amdgcn_mfma_f32_16x16x32_bf16(X[fb][ks], Y[ks], acc[fb], 0, 0, 0);
            }

            __syncthreads();   // previous iteration's reads done before rewrite

            if (active) {
                #pragma unroll
                for (int fb = 0; fb < 8; ++fb) {
                    uint2 d;
                    d.x = (unsigned)f2bf(acc[fb][0]) | ((unsigned)f2bf(acc[fb][1]) << 16);
                    d.y = (unsigned)f2bf(acc[fb][2]) | ((unsigned)f2bf(acc[fb][3]) << 16);
                    *reinterpret_cast<uint2*>(&S[lane & 15][fb * 16 + (lane >> 4) * 4]) = d;
                }
            }

            __syncthreads();   // writes visible before cross-lane reads

            if (active) {
                #pragma unroll
                for (int i = 0; i < 4; ++i) {
                    const int row  = i * 4 + (lane >> 4);
                    const int node = mb * 16 + row;
                    if (node < n_nodes) {
                        uint4 v = *reinterpret_cast<const uint4*>(&S[row][(lane & 15) * 8]);
                        *reinterpret_cast<uint4*>(
                            proj + ((size_t)rr * n_nodes + node) * FEAT + (lane & 15) * 8) = v;
                    }
                }
            }
        }
    }
}

// ---------------------------------------------------------------------------
// bgather: one 512-thread block per bucket. LDS counting-sort of the bucket's
// records, then 16-lane groups consume their node's contiguous run via LDS
// broadcast reads. Register accumulation, 3-deep prefetch, fused ReLU,
// coalesced float4 stores. Overflow records (edge indices) replayed per-group.
// ---------------------------------------------------------------------------
__global__ __launch_bounds__(512) void bgather_kernel(
    const ushort* __restrict__ proj, const uint2* __restrict__ rtmp,
    const int* __restrict__ gcur, const int* __restrict__ ovf,
    const int* __restrict__ src, const int* __restrict__ dst,
    const int* __restrict__ rel, const float* __restrict__ norm,
    float* __restrict__ out, int n_nodes, int nbkt)
{
    __shared__ uint2 sorted[CAP];          // 16 KB
    __shared__ int cnt[BKT_SZ], cur[BKT_SZ], nbeg[BKT_SZ];

    const int b   = blockIdx.x;
    const int tid = threadIdx.x;
    const uint2* slab = rtmp + (size_t)b * CAP;

    const int total = gcur[b];
    const int n = (total < CAP) ? total : CAP;

    if (tid < BKT_SZ) cnt[tid] = 0;
    __syncthreads();
    for (int i = tid; i < n; i += 512)
        atomicAdd(&cnt[(slab[i].x >> 19) & 31u], 1);
    __syncthreads();
    if (tid == 0) {
        int run = 0;
        for (int k = 0; k < BKT_SZ; ++k) { nbeg[k] = run; cur[k] = run; run += cnt[k]; }
    }
    __syncthreads();
    for (int i = tid; i < n; i += 512) {
        uint2 r = slab[i];                          // L2-hot second read
        int p = atomicAdd(&cur[(r.x >> 19) & 31u], 1);
        sorted[p] = r;
    }
    __syncthreads();

    // ---- per-group gather ----
    const int lane = tid & 63;
    const int wv   = tid >> 6;            // 0..7
    const int grp  = lane >> 4;           // 0..3
    const int sl   = lane & 15;
    const int k    = wv * 4 + grp;        // node-in-bucket 0..31
    const int node = b * BKT_SZ + k;
    if (node >= n_nodes) return;

    float a0 = 0.f, a1 = 0.f, a2 = 0.f, a3 = 0.f;
    float a4 = 0.f, a5 = 0.f, a6 = 0.f, a7 = 0.f;

    const int s0 = nbeg[k];
    const int s1 = s0 + cnt[k];

    uint4 va, vb, vc;
    unsigned nm0 = 0, nm1 = 0, nm2 = 0;
    va = vb = vc = make_uint4(0u, 0u, 0u, 0u);
    if (s0 < s1) {
        uint2 r = sorted[s0]; nm0 = r.y;
        va = *reinterpret_cast<const uint4*>(proj +
            ((size_t)((r.x >> 15) & 0xfu) * n_nodes + (r.x & 0x7fffu)) * FEAT + sl * 8);
    }
    if (s0 + 1 < s1) {
        uint2 r = sorted[s0 + 1]; nm1 = r.y;
        vb = *reinterpret_cast<const uint4*>(proj +
            ((size_t)((r.x >> 15) & 0xfu) * n_nodes + (r.x & 0x7fffu)) * FEAT + sl * 8);
    }
    if (s0 + 2 < s1) {
        uint2 r = sorted[s0 + 2]; nm2 = r.y;
        vc = *reinterpret_cast<const uint4*>(proj +
            ((size_t)((r.x >> 15) & 0xfu) * n_nodes + (r.x & 0x7fffu)) * FEAT + sl * 8);
    }

    for (int s = s0; s < s1; ++s) {
        uint4 vcur = va; unsigned nmu = nm0;
        va = vb; nm0 = nm1;
        vb = vc; nm1 = nm2;
        if (s + 3 < s1) {
            uint2 r = sorted[s + 3]; nm2 = r.y;
            vc = *reinterpret_cast<const uint4*>(proj +
                ((size_t)((r.x >> 15) & 0xfu) * n_nodes + (r.x & 0x7fffu)) * FEAT + sl * 8);
        }
        float nmc = __uint_as_float(nmu);
        a0 += bf2f((ushort)(vcur.x & 0xffffu)) * nmc;
        a1 += bf2f((ushort)(vcur.x >> 16)) * nmc;
        a2 += bf2f((ushort)(vcur.y & 0xffffu)) * nmc;
        a3 += bf2f((ushort)(vcur.y >> 16)) * nmc;
        a4 += bf2f((ushort)(vcur.z & 0xffffu)) * nmc;
        a5 += bf2f((ushort)(vcur.z >> 16)) * nmc;
        a6 += bf2f((ushort)(vcur.w & 0xffffu)) * nmc;
        a7 += bf2f((ushort)(vcur.w >> 16)) * nmc;
    }

    // ---- overflow replay (practically never taken) ----
    const int novf = gcur[nbkt];
    for (int i = 0; i < novf; ++i) {
        int e = ovf[i];
        if (dst[e] == node) {
            float nmc = norm[e];
            const ushort* prow = proj +
                ((size_t)rel[e] * n_nodes + src[e]) * FEAT + sl * 8;
            uint4 v = *reinterpret_cast<const uint4*>(prow);
            a0 += bf2f((ushort)(v.x & 0xffffu)) * nmc;
            a1 += bf2f((ushort)(v.x >> 16)) * nmc;
            a2 += bf2f((ushort)(v.y & 0xffffu)) * nmc;
            a3 += bf2f((ushort)(v.y >> 16)) * nmc;
            a4 += bf2f((ushort)(v.z & 0xffffu)) * nmc;
            a5 += bf2f((ushort)(v.z >> 16)) * nmc;
            a6 += bf2f((ushort)(v.w & 0xffffu)) * nmc;
            a7 += bf2f((ushort)(v.w >> 16)) * nmc;
        }
    }

    float* o = out + (size_t)node * FEAT + sl * 8;
    float4 o0, o1;
    o0.x = fmaxf(a0, 0.f); o0.y = fmaxf(a1, 0.f);
    o0.z = fmaxf(a2, 0.f); o0.w = fmaxf(a3, 0.f);
    o1.x = fmaxf(a4, 0.f); o1.y = fmaxf(a5, 0.f);
    o1.z = fmaxf(a6, 0.f); o1.w = fmaxf(a7, 0.f);
    *reinterpret_cast<float4*>(o)     = o0;
    *reinterpret_cast<float4*>(o + 4) = o1;
}

// ---------------------------------------------------------------------------
// Fallback (small ws): LDS proj + atomic edge path
// ---------------------------------------------------------------------------
constexpr int BM = 64;

__global__ __launch_bounds__(256) void proj_kernel(
    const float* __restrict__ h, const float* __restrict__ W,
    ushort* __restrict__ proj, int n_nodes, int r0)
{
    __shared__ ushort Wt[128][136];
    __shared__ ushort hs[BM][136];

    const int tid  = threadIdx.x;
    const int rel  = r0 + blockIdx.y;
    const float* Wg = W + (size_t)rel * FEAT * FEAT;

    #pragma unroll
    for (int it = 0; it < 16; ++it) {
        int f = (it * 256 + tid) * 4;
        int k = f >> 7, n = f & 127;
        float4 w4 = *reinterpret_cast<const float4*>(Wg + f);
        Wt[n + 0][k] = f2bf(w4.x);
        Wt[n + 1][k] = f2bf(w4.y);
        Wt[n + 2][k] = f2bf(w4.z);
        Wt[n + 3][k] = f2bf(w4.w);
    }

    const int lane = tid & 63;
    const int wave = tid >> 6;
    const int r    = lane & 15;
    const int kgrp = lane >> 4;

    ushort* projr = proj + (size_t)blockIdx.y * n_nodes * FEAT;
    const int nchunks = (n_nodes + BM - 1) / BM;

    for (int c = blockIdx.x; c < nchunks; c += gridDim.x) {
        const int m0 = c * BM;
        __syncthreads();
        #pragma unroll
        for (int it = 0; it < 8; ++it) {
            int f = (it * 256 + tid) * 4;
            int m = f >> 7, k = f & 127;
            int row = m0 + m;
            float4 v = make_float4(0.f, 0.f, 0.f, 0.f);
            if (row < n_nodes)
                v = *reinterpret_cast<const float4*>(h + (size_t)row * FEAT + k);
            ushort4 u;
            u.x = f2bf(v.x); u.y = f2bf(v.y); u.z = f2bf(v.z); u.w = f2bf(v.w);
            *reinterpret_cast<ushort4*>(&hs[m][k]) = u;
        }
        __syncthreads();

        f32x4 acc[8];
        #pragma unroll
        for (int i = 0; i < 8; ++i) acc[i] = f32x4{0.f, 0.f, 0.f, 0.f};

        #pragma unroll
        for (int kk = 0; kk < 4; ++kk) {
            const int kbase = kk * 32 + kgrp * 8;
            short8 a = *reinterpret_cast<const short8*>(&hs[wave * 16 + r][kbase]);
            #pragma unroll
            for (int ct = 0; ct < 8; ++ct) {
                short8 b = *reinterpret_cast<const short8*>(&Wt[ct * 16 + r][kbase]);
                acc[ct] = __builtin_amdgcn_mfma_f32_16x16x32_bf16(a, b, acc[ct], 0, 0, 0);
            }
        }

        #pragma unroll
        for (int ct = 0; ct < 8; ++ct) {
            #pragma unroll
            for (int i = 0; i < 4; ++i) {
                int row = m0 + wave * 16 + kgrp * 4 + i;
                if (row < n_nodes)
                    projr[(size_t)row * FEAT + ct * 16 + r] = f2bf(acc[ct][i]);
            }
        }
    }
}

__global__ __launch_bounds__(256) void edge_kernel(
    const ushort* __restrict__ proj, const float* __restrict__ norm,
    const int* __restrict__ src, const int* __restrict__ dst,
    const int* __restrict__ rel, float* __restrict__ out,
    int n_edges, int n_nodes, int r0, int r1)
{
    const int lane = threadIdx.x & 63;
    int gw = (int)((blockIdx.x * blockDim.x + threadIdx.x) >> 6);
    const int nw = (int)((gridDim.x * blockDim.x) >> 6);

    for (int e = gw; e < n_edges; e += nw) {
        int rr = rel[e];
        if (rr < r0 || rr >= r1) continue;
        int s = src[e];
        int d = dst[e];
        float nm = norm[e];
        const ushort* prow = proj + ((size_t)(rr - r0) * n_nodes + s) * FEAT;
        unsigned int v = *reinterpret_cast<const unsigned int*>(prow + lane * 2);
        float x0 = bf2f((ushort)(v & 0xffffu)) * nm;
        float x1 = bf2f((ushort)(v >> 16)) * nm;
        float* o = out + (size_t)d * FEAT + lane * 2;
        atomicAdd(o + 0, x0);
        atomicAdd(o + 1, x1);
    }
}

__global__ __launch_bounds__(256) void relu_kernel(float4* out, int n4)
{
    int i = blockIdx.x * blockDim.x + threadIdx.x;
    int stride = gridDim.x * blockDim.x;
    for (; i < n4; i += stride) {
        float4 v = out[i];
        v.x = fmaxf(v.x, 0.f);
        v.y = fmaxf(v.y, 0.f);
        v.z = fmaxf(v.z, 0.f);
        v.w = fmaxf(v.w, 0.f);
        out[i] = v;
    }
}

extern "C" void kernel_launch(void* const* d_in, const int* in_sizes, int n_in,
                              void* d_out, int out_size, void* d_ws, size_t ws_size,
                              hipStream_t stream)
{
    const float* h    = (const float*)d_in[0];
    const float* W    = (const float*)d_in[1];
    const float* norm = (const float*)d_in[2];
    const int*   src  = (const int*)d_in[3];
    const int*   dst  = (const int*)d_in[4];
    const int*   rel  = (const int*)d_in[5];
    float* out = (float*)d_out;

    const int n_nodes = in_sizes[0] / FEAT;   // 20000
    const int n_edges = in_sizes[3];          // 640000
    const int nmblk   = (n_nodes + 15) / 16;
    const int nbkt    = (n_nodes + BKT_SZ - 1) / BKT_SZ;   // 625
    const int nchunks = (n_edges + PCHUNK - 1) / PCHUNK;   // 157

    // ws layout
    const size_t projB    = (size_t)NRELS * n_nodes * FEAT * sizeof(ushort);
    const size_t rtmpOff  = (projB + 255) & ~(size_t)255;
    const size_t rtmpB    = (size_t)nbkt * CAP * sizeof(uint2);
    const size_t ovfOff   = (rtmpOff + rtmpB + 255) & ~(size_t)255;
    const size_t ovfB     = (size_t)n_edges * sizeof(int);
    const size_t gcurOff  = (ovfOff + ovfB + 255) & ~(size_t)255;
    const size_t gcurB    = ((size_t)(nbkt + 1) * 4 + 255) & ~(size_t)255;
    const size_t hpackOff = gcurOff + gcurB;
    const size_t hpackB   = ((size_t)nmblk * 256 * 8 * sizeof(ushort) + 255) & ~(size_t)255;
    const size_t wpackOff = hpackOff + hpackB;
    const size_t wpackB   = (size_t)NRELS * 8 * 4 * 64 * 8 * sizeof(ushort);
    const size_t need     = wpackOff + wpackB;

    if (ws_size >= need && n_nodes < 32768 && nbkt <= 1024) {
        ushort* proj   = (ushort*)d_ws;
        uint2*  rtmp   = (uint2*)((char*)d_ws + rtmpOff);
        int*    ovf    = (int*)((char*)d_ws + ovfOff);
        int*    gcur   = (int*)((char*)d_ws + gcurOff);
        ushort* hpack  = (ushort*)((char*)d_ws + hpackOff);
        ushort* wpack  = (ushort*)((char*)d_ws + wpackOff);

        prep_kernel<<<nmblk + 128 + 1, 256, 0, stream>>>(
            h, W, hpack, wpack, gcur, n_nodes, nmblk, nbkt);

        fused2_kernel<<<nchunks + NRELS * 128, 256, 0, stream>>>(
            hpack, wpack, proj, src, dst, rel, norm, gcur, rtmp, ovf,
            n_nodes, nmblk, n_edges, nbkt, nchunks);

        bgather_kernel<<<nbkt, 512, 0, stream>>>(
            proj, rtmp, gcur, ovf, src, dst, rel, norm, out, n_nodes, nbkt);
    } else {
        // fallback: relation-chunked atomic path
        ushort* proj = (ushort*)d_ws;
        hipMemsetAsync(out, 0, (size_t)out_size * sizeof(float), stream);
        const size_t perRel = (size_t)n_nodes * FEAT * sizeof(ushort);
        int rc = (int)(ws_size / perRel);
        if (rc < 1) rc = 1;
        if (rc > NRELS) rc = NRELS;
        for (int r0 = 0; r0 < NRELS; r0 += rc) {
            const int rcc = (rc < NRELS - r0) ? rc : (NRELS - r0);
            dim3 g1(32, rcc);
            proj_kernel<<<g1, 256, 0, stream>>>(h, W, proj, n_nodes, r0);
            edge_kernel<<<1024, 256, 0, stream>>>(proj, norm, src, dst, rel, out,
                                                  n_edges, n_nodes, r0, r0 + rcc);
        }
        relu_kernel<<<2048, 256, 0, stream>>>((float4*)out, out_size / 4);
    }
}